// Round 9
// baseline (791.095 us; speedup 1.0000x reference)
//
#include <hip/hip_runtime.h>
#include <stdint.h>

#define M_TOT  9216   // 16*576
#define D_     768
#define CIN_   1024
#define KCODE  8192
#define TOPK   10

typedef unsigned short u16;
typedef __bf16 bf16x8 __attribute__((ext_vector_type(8)));
typedef float f32x4 __attribute__((ext_vector_type(4)));

// ---------------- helpers ----------------

__device__ inline float block_sum(float v, float* red) {
    int t = threadIdx.x;
    red[t] = v;
    __syncthreads();
    #pragma unroll
    for (int s = 128; s > 0; s >>= 1) {
        if (t < s) red[t] += red[t + s];
        __syncthreads();
    }
    float r = red[0];
    __syncthreads();
    return r;
}

__device__ inline unsigned long long umin64(unsigned long long a, unsigned long long b) {
    return (a < b) ? a : b;
}

__device__ inline u16 f2bf(float f) {          // RNE f32 -> bf16
    uint32_t u = __float_as_uint(f);
    uint32_t r = (u + 0x7fffu + ((u >> 16) & 1u)) >> 16;
    return (u16)r;
}
__device__ inline float bf2f(u16 h) {
    return __uint_as_float(((uint32_t)h) << 16);
}

__device__ inline unsigned long long shfl_xor_u64(unsigned long long v, int mask) {
    int lo = (int)(uint32_t)v, hi = (int)(uint32_t)(v >> 32);
    lo = __shfl_xor(lo, mask, 64);
    hi = __shfl_xor(hi, mask, 64);
    return ((unsigned long long)(uint32_t)hi << 32) | (uint32_t)lo;
}

#define GLDS(gp, lp) __builtin_amdgcn_global_load_lds( \
    (const __attribute__((address_space(1))) unsigned int*)(gp), \
    (__attribute__((address_space(3))) unsigned int*)(lp), 16, 0, 0)

// BK=32 XOR-swizzled LDS layout (per matrix 4096 u16 = 8KB, rows of 32 u16):
//   logical k-chunk kc (of 8 u16) of row r lives at phys slot kc ^ ((r>>1)&3).
//   Staging (linear dest c*512+lane*8): row = c*16+(lane>>2), phys slot lane&3
//     => source k-chunk = (lane&3) ^ ((lane>>3)&3); 4 lanes cover each row's
//     64B line (coalesced).
//   Reads: slot = (kb ^ ((r16>>1)&3)); bank spread = 2-way (free, m136).

// ---------------- GEMM1: 3-way-split bf16 MFMA, 6 terms, swizzled reads -------
__global__ __launch_bounds__(256) void k_gemm1_mfma(
    const u16* __restrict__ Ah, const u16* __restrict__ Am, const u16* __restrict__ Al,
    const u16* __restrict__ Bh, const u16* __restrict__ Bm, const u16* __restrict__ Bl,
    const float* __restrict__ bias, float* __restrict__ C)
{
    __shared__ __align__(16) u16 sm[24576];   // 48KB: Ah|Am|Al|Bh|Bm|Bl, 4096 u16 each
    const int t = threadIdx.x;
    const int lane = t & 63, wid = t >> 6;
    const int row0 = blockIdx.y * 128, col0 = blockIdx.x * 128;
    const int r16 = lane & 15, kb = lane >> 4;
    const int wr = wid >> 1, wc = wid & 1;
    const int sc = (((lane & 3) ^ ((lane >> 3) & 3))) * 8;
    const int lrow = lane >> 2;
    const int swz = (r16 >> 1) & 3;

    f32x4 acc[4][4];
    #pragma unroll
    for (int mf = 0; mf < 4; ++mf)
        #pragma unroll
        for (int nf = 0; nf < 4; ++nf)
            acc[mf][nf] = (f32x4){0.f, 0.f, 0.f, 0.f};

    for (int k0 = 0; k0 < CIN_; k0 += 32) {
        __syncthreads();
        #pragma unroll
        for (int i = 0; i < 12; ++i) {
            int mat = i >> 1;
            int c = (i & 1) ? wid + 4 : wid;
            const u16* mp = (mat == 0) ? Ah : (mat == 1) ? Am : (mat == 2) ? Al
                          : (mat == 3) ? Bh : (mat == 4) ? Bm : Bl;
            int rbase = (mat < 3) ? row0 : col0;
            const u16* g = mp + (size_t)(rbase + c * 16 + lrow) * CIN_ + k0 + sc;
            GLDS(g, sm + mat * 4096 + c * 512);
        }
        __syncthreads();

        const int slot = (kb ^ swz) * 8;
        bf16x8 bh[4], bm[4], bl[4];
        #pragma unroll
        for (int nf = 0; nf < 4; ++nf) {
            int offb = 12288 + (wc * 64 + nf * 16 + r16) * 32 + slot;
            bh[nf] = *(const bf16x8*)(sm + offb);
            bm[nf] = *(const bf16x8*)(sm + offb + 4096);
            bl[nf] = *(const bf16x8*)(sm + offb + 8192);
        }
        #pragma unroll
        for (int mf = 0; mf < 4; ++mf) {
            int offa = (wr * 64 + mf * 16 + r16) * 32 + slot;
            bf16x8 ah = *(const bf16x8*)(sm + offa);
            bf16x8 am = *(const bf16x8*)(sm + offa + 4096);
            bf16x8 al = *(const bf16x8*)(sm + offa + 8192);
            #pragma unroll
            for (int nf = 0; nf < 4; ++nf) {
                acc[mf][nf] = __builtin_amdgcn_mfma_f32_16x16x32_bf16(ah, bh[nf], acc[mf][nf], 0, 0, 0);
                acc[mf][nf] = __builtin_amdgcn_mfma_f32_16x16x32_bf16(ah, bm[nf], acc[mf][nf], 0, 0, 0);
                acc[mf][nf] = __builtin_amdgcn_mfma_f32_16x16x32_bf16(am, bh[nf], acc[mf][nf], 0, 0, 0);
                acc[mf][nf] = __builtin_amdgcn_mfma_f32_16x16x32_bf16(am, bm[nf], acc[mf][nf], 0, 0, 0);
                acc[mf][nf] = __builtin_amdgcn_mfma_f32_16x16x32_bf16(ah, bl[nf], acc[mf][nf], 0, 0, 0);
                acc[mf][nf] = __builtin_amdgcn_mfma_f32_16x16x32_bf16(al, bh[nf], acc[mf][nf], 0, 0, 0);
            }
        }
    }

    #pragma unroll
    for (int mf = 0; mf < 4; ++mf) {
        #pragma unroll
        for (int q = 0; q < 4; ++q) {
            int m = row0 + wr * 64 + mf * 16 + kb * 4 + q;
            #pragma unroll
            for (int nf = 0; nf < 4; ++nf) {
                int n = col0 + wc * 64 + nf * 16 + r16;
                C[(size_t)m * D_ + n] = acc[mf][nf][q] + bias[n];
            }
        }
    }
}

// ---------------- GEMM3: 2-way-split MFMA, BK=32 swizzled dbuf, A gathered ----
__global__ __launch_bounds__(256) void k_gemm3_mfma(
    const u16* __restrict__ Eh, const u16* __restrict__ El,
    const u16* __restrict__ Ph, const u16* __restrict__ Pl,
    const int* __restrict__ gather,
    const float* __restrict__ bias, float* __restrict__ C)
{
    __shared__ __align__(16) u16 sm[2][16384];   // 2 x 32KB: Ah|Al|Bh|Bl
    const int t = threadIdx.x;
    const int lane = t & 63, wid = t >> 6;
    const int row0 = blockIdx.y * 128, col0 = blockIdx.x * 128;
    const int r16 = lane & 15, kb = lane >> 4;
    const int wr = wid >> 1, wc = wid & 1;
    const int sc = (((lane & 3) ^ ((lane >> 3) & 3))) * 8;
    const int lrow = lane >> 2;
    const int swz = (r16 >> 1) & 3;

    const u16* sb = (wid == 0) ? Eh : (wid == 1) ? El : (wid == 2) ? Ph : Pl;
    int grow[8];
    #pragma unroll
    for (int c = 0; c < 8; ++c) {
        int r = ((wid < 2) ? row0 : col0) + c * 16 + lrow;
        grow[c] = (wid < 2) ? gather[r] : r;
    }

    f32x4 acc[4][4];
    #pragma unroll
    for (int mf = 0; mf < 4; ++mf)
        #pragma unroll
        for (int nf = 0; nf < 4; ++nf)
            acc[mf][nf] = (f32x4){0.f, 0.f, 0.f, 0.f};

    auto STAGE = [&](int buf, int k0) {
        u16* dst = sm[buf] + wid * 4096 + lane * 8;
        #pragma unroll
        for (int c = 0; c < 8; ++c)
            GLDS(sb + (size_t)grow[c] * D_ + k0 + sc, dst + c * 512);
    };

    STAGE(0, 0);
    __syncthreads();
    for (int kt = 0; kt < 24; ++kt) {
        int cur = kt & 1;
        if (kt < 23) STAGE(cur ^ 1, (kt + 1) * 32);
        const u16* B = sm[cur];
        const int slot = (kb ^ swz) * 8;
        bf16x8 bh[4], bl[4];
        #pragma unroll
        for (int nf = 0; nf < 4; ++nf) {
            int off = 8192 + (wc * 64 + nf * 16 + r16) * 32 + slot;
            bh[nf] = *(const bf16x8*)(B + off);
            bl[nf] = *(const bf16x8*)(B + off + 4096);
        }
        #pragma unroll
        for (int mf = 0; mf < 4; ++mf) {
            int off = (wr * 64 + mf * 16 + r16) * 32 + slot;
            bf16x8 ah = *(const bf16x8*)(B + off);
            bf16x8 al = *(const bf16x8*)(B + off + 4096);
            #pragma unroll
            for (int nf = 0; nf < 4; ++nf) {
                acc[mf][nf] = __builtin_amdgcn_mfma_f32_16x16x32_bf16(ah, bh[nf], acc[mf][nf], 0, 0, 0);
                acc[mf][nf] = __builtin_amdgcn_mfma_f32_16x16x32_bf16(ah, bl[nf], acc[mf][nf], 0, 0, 0);
                acc[mf][nf] = __builtin_amdgcn_mfma_f32_16x16x32_bf16(al, bh[nf], acc[mf][nf], 0, 0, 0);
            }
        }
        __syncthreads();
    }

    #pragma unroll
    for (int mf = 0; mf < 4; ++mf) {
        #pragma unroll
        for (int q = 0; q < 4; ++q) {
            int m = row0 + wr * 64 + mf * 16 + kb * 4 + q;
            #pragma unroll
            for (int nf = 0; nf < 4; ++nf) {
                int n = col0 + wc * 64 + nf * 16 + r16;
                C[(size_t)m * D_ + n] = acc[mf][nf][q] + bias[n];
            }
        }
    }
}

// ---------------- rowflag: mark the 16 masked rows ----------------
__global__ void k_rowflag(const int* __restrict__ mask, int* __restrict__ rowflag)
{
    int i = blockIdx.x * 256 + threadIdx.x;
    if (i < M_TOT) {
        int b = i / 576, l = i - b * 576;
        rowflag[i] = (mask[b] == l) ? (b + 1) : 0;
    }
}

// ---------------- GEMM2: split-bf16 MFMA, BK=32 swizzled, 64KB dbuf -----------
// 2 blocks/CU preserved (2x32KB); next-tile loads in flight across the barrier.
// Fused d2 + argmin + masked-row d2 capture.
__global__ __launch_bounds__(256) void k_gemm2_mfma(
    const u16* __restrict__ Xh, const u16* __restrict__ Xl,
    const u16* __restrict__ Eh, const u16* __restrict__ El,
    const float* __restrict__ xsq, const float* __restrict__ esq,
    const int* __restrict__ rowflag, float* __restrict__ d2row,
    unsigned long long* __restrict__ amin)
{
    __shared__ __align__(16) u16 sm[2][16384];   // 2 x 32KB: Ah|Al|Bh|Bl
    const int t = threadIdx.x;
    const int lane = t & 63, wid = t >> 6;
    const int row0 = blockIdx.y * 128, col0 = blockIdx.x * 128;
    const int r16 = lane & 15, kb = lane >> 4;
    const int wr = wid >> 1, wc = wid & 1;
    const int sc = (((lane & 3) ^ ((lane >> 3) & 3))) * 8;
    const int lrow = lane >> 2;
    const int swz = (r16 >> 1) & 3;

    f32x4 acc[4][4];
    #pragma unroll
    for (int mf = 0; mf < 4; ++mf)
        #pragma unroll
        for (int nf = 0; nf < 4; ++nf)
            acc[mf][nf] = (f32x4){0.f, 0.f, 0.f, 0.f};

    const u16* sb = (wid == 0) ? Xh : (wid == 1) ? Xl : (wid == 2) ? Eh : El;
    const int rbase = (wid < 2) ? row0 : col0;
    const u16* srcb = sb + (size_t)(rbase + lrow) * D_ + sc;

    auto STAGE = [&](int buf, int k0) {
        u16* dst = sm[buf] + wid * 4096 + lane * 8;
        #pragma unroll
        for (int c = 0; c < 8; ++c)
            GLDS(srcb + (size_t)c * 16 * D_ + k0, dst + c * 512);
    };

    STAGE(0, 0);
    __syncthreads();
    for (int kt = 0; kt < 24; ++kt) {
        int cur = kt & 1;
        if (kt < 23) STAGE(cur ^ 1, (kt + 1) * 32);
        const u16* B = sm[cur];
        const int slot = (kb ^ swz) * 8;
        bf16x8 bh[4], bl[4];
        #pragma unroll
        for (int nf = 0; nf < 4; ++nf) {
            int off = 8192 + (wc * 64 + nf * 16 + r16) * 32 + slot;
            bh[nf] = *(const bf16x8*)(B + off);
            bl[nf] = *(const bf16x8*)(B + off + 4096);
        }
        #pragma unroll
        for (int mf = 0; mf < 4; ++mf) {
            int off = (wr * 64 + mf * 16 + r16) * 32 + slot;
            bf16x8 ah = *(const bf16x8*)(B + off);
            bf16x8 al = *(const bf16x8*)(B + off + 4096);
            #pragma unroll
            for (int nf = 0; nf < 4; ++nf) {
                acc[mf][nf] = __builtin_amdgcn_mfma_f32_16x16x32_bf16(ah, bh[nf], acc[mf][nf], 0, 0, 0);
                acc[mf][nf] = __builtin_amdgcn_mfma_f32_16x16x32_bf16(ah, bl[nf], acc[mf][nf], 0, 0, 0);
                acc[mf][nf] = __builtin_amdgcn_mfma_f32_16x16x32_bf16(al, bh[nf], acc[mf][nf], 0, 0, 0);
            }
        }
        __syncthreads();
    }

    float esqv[4];
    #pragma unroll
    for (int nf = 0; nf < 4; ++nf)
        esqv[nf] = esq[col0 + wc * 64 + nf * 16 + r16];

    #pragma unroll
    for (int mf = 0; mf < 4; ++mf) {
        #pragma unroll
        for (int q = 0; q < 4; ++q) {
            int m = row0 + wr * 64 + mf * 16 + kb * 4 + q;
            float xsv = xsq[m];
            int rf = rowflag[m];
            unsigned long long best = ~0ull;
            #pragma unroll
            for (int nf = 0; nf < 4; ++nf) {
                int n = col0 + wc * 64 + nf * 16 + r16;
                float d2 = (xsv - 2.0f * acc[mf][nf][q]) + esqv[nf];
                if (rf) d2row[(size_t)(rf - 1) * KCODE + n] = d2;
                unsigned long long key =
                    ((unsigned long long)__float_as_uint(d2) << 32) | (unsigned)n;
                best = umin64(best, key);
            }
            #pragma unroll
            for (int msk = 1; msk < 16; msk <<= 1)
                best = umin64(best, shfl_xor_u64(best, msk));
            if (r16 == 0) atomicMin(&amin[m], best);
        }
    }
}

// ---------------- splits ----------------
__global__ __launch_bounds__(256) void k_split3(const float* __restrict__ in,
    u16* __restrict__ h, u16* __restrict__ m, u16* __restrict__ l, int n4)
{
    int i = blockIdx.x * 256 + threadIdx.x;
    int stride = gridDim.x * 256;
    for (; i < n4; i += stride) {
        float4 v = ((const float4*)in)[i];
        ushort4 hv, mv, lv;
        float x, r;
        x = v.x; hv.x = f2bf(x); r = x - bf2f(hv.x); mv.x = f2bf(r); lv.x = f2bf(r - bf2f(mv.x));
        x = v.y; hv.y = f2bf(x); r = x - bf2f(hv.y); mv.y = f2bf(r); lv.y = f2bf(r - bf2f(mv.y));
        x = v.z; hv.z = f2bf(x); r = x - bf2f(hv.z); mv.z = f2bf(r); lv.z = f2bf(r - bf2f(mv.z));
        x = v.w; hv.w = f2bf(x); r = x - bf2f(hv.w); mv.w = f2bf(r); lv.w = f2bf(r - bf2f(mv.w));
        ((ushort4*)h)[i] = hv; ((ushort4*)m)[i] = mv; ((ushort4*)l)[i] = lv;
    }
}

__global__ __launch_bounds__(256) void k_split2(const float* __restrict__ in,
    u16* __restrict__ h, u16* __restrict__ l, int n4)
{
    int i = blockIdx.x * 256 + threadIdx.x;
    int stride = gridDim.x * 256;
    for (; i < n4; i += stride) {
        float4 v = ((const float4*)in)[i];
        ushort4 hv, lv;
        hv.x = f2bf(v.x); lv.x = f2bf(v.x - bf2f(hv.x));
        hv.y = f2bf(v.y); lv.y = f2bf(v.y - bf2f(hv.y));
        hv.z = f2bf(v.z); lv.z = f2bf(v.z - bf2f(hv.z));
        hv.w = f2bf(v.w); lv.w = f2bf(v.w - bf2f(hv.w));
        ((ushort4*)h)[i] = hv; ((ushort4*)l)[i] = lv;
    }
}

// ---------------- LN1 + ReLU + row sum of squares + bf16 split ----------------
__global__ __launch_bounds__(256) void k_ln_relu(
    const float* __restrict__ in, const float* __restrict__ w,
    const float* __restrict__ b, float* __restrict__ xq, float* __restrict__ xsq,
    u16* __restrict__ Xh, u16* __restrict__ Xl)
{
    __shared__ float red[256];
    int r = blockIdx.x, t = threadIdx.x;
    const float* row = in + (size_t)r * D_;
    float v0 = row[t], v1 = row[t + 256], v2 = row[t + 512];
    float mu = block_sum(v0 + v1 + v2, red) * (1.0f / 768.0f);
    float d0 = v0 - mu, d1 = v1 - mu, d2 = v2 - mu;
    float var = block_sum(d0 * d0 + d1 * d1 + d2 * d2, red) * (1.0f / 768.0f);
    float rn = 1.0f / sqrtf(var + 1e-5f);
    float o0 = fmaxf(0.0f, d0 * rn * w[t] + b[t]);
    float o1 = fmaxf(0.0f, d1 * rn * w[t + 256] + b[t + 256]);
    float o2 = fmaxf(0.0f, d2 * rn * w[t + 512] + b[t + 512]);
    float* orow = xq + (size_t)r * D_;
    orow[t] = o0; orow[t + 256] = o1; orow[t + 512] = o2;
    u16 h0 = f2bf(o0), h1 = f2bf(o1), h2 = f2bf(o2);
    Xh[(size_t)r * D_ + t]       = h0;
    Xh[(size_t)r * D_ + t + 256] = h1;
    Xh[(size_t)r * D_ + t + 512] = h2;
    Xl[(size_t)r * D_ + t]       = f2bf(o0 - bf2f(h0));
    Xl[(size_t)r * D_ + t + 256] = f2bf(o1 - bf2f(h1));
    Xl[(size_t)r * D_ + t + 512] = f2bf(o2 - bf2f(h2));
    float q = block_sum(o0 * o0 + o1 * o1 + o2 * o2, red);
    if (t == 0) xsq[r] = q;
}

// ---------------- codebook row norms + bf16 split ----------------
__global__ __launch_bounds__(256) void k_esq(const float* __restrict__ E,
                                             float* __restrict__ esq,
                                             u16* __restrict__ Eh,
                                             u16* __restrict__ El)
{
    __shared__ float red[256];
    int r = blockIdx.x, t = threadIdx.x;
    const float* row = E + (size_t)r * D_;
    float v0 = row[t], v1 = row[t + 256], v2 = row[t + 512];
    u16 h0 = f2bf(v0), h1 = f2bf(v1), h2 = f2bf(v2);
    Eh[(size_t)r * D_ + t]       = h0;
    Eh[(size_t)r * D_ + t + 256] = h1;
    Eh[(size_t)r * D_ + t + 512] = h2;
    El[(size_t)r * D_ + t]       = f2bf(v0 - bf2f(h0));
    El[(size_t)r * D_ + t + 256] = f2bf(v1 - bf2f(h1));
    El[(size_t)r * D_ + t + 512] = f2bf(v2 - bf2f(h2));
    float s = block_sum(v0 * v0 + v1 * v1 + v2 * v2, red);
    if (t == 0) esq[r] = s;
}

__global__ void k_extract(const unsigned long long* __restrict__ amin,
                          int* __restrict__ idx, int n)
{
    int i = blockIdx.x * 256 + threadIdx.x;
    if (i < n) idx[i] = (int)(amin[i] & 0xFFFFFFFFull);
}

// ---------------- gate: 2-wide GEMV + LN(2) + relu + softmax ----------------
__global__ __launch_bounds__(256) void k_gate(
    const float* __restrict__ embpt, const float* __restrict__ xq,
    const float* __restrict__ gw, const float* __restrict__ gb,
    const float* __restrict__ glnw, const float* __restrict__ glnb,
    float* __restrict__ scores)
{
    __shared__ float red[256];
    int r = blockIdx.x, t = threadIdx.x;
    const float* ep = embpt + (size_t)r * D_;
    const float* xr = xq + (size_t)r * D_;
    float g0 = 0.0f, g1 = 0.0f;
    for (int k = t; k < 1536; k += 256) {
        float v = (k < 768) ? ep[k] : xr[k - 768];
        g0 = fmaf(v, gw[k], g0);
        g1 = fmaf(v, gw[1536 + k], g1);
    }
    g0 = block_sum(g0, red);
    g1 = block_sum(g1, red);
    if (t == 0) {
        g0 += gb[0]; g1 += gb[1];
        float mu = 0.5f * (g0 + g1);
        float h0 = g0 - mu, h1 = g1 - mu;
        float var = 0.5f * (h0 * h0 + h1 * h1);
        float rn = 1.0f / sqrtf(var + 1e-5f);
        float o0 = fmaxf(0.0f, h0 * rn * glnw[0] + glnb[0]);
        float o1 = fmaxf(0.0f, h1 * rn * glnw[1] + glnb[1]);
        float m = fmaxf(o0, o1);
        float e0 = expf(o0 - m), e1 = expf(o1 - m);
        float inv = 1.0f / (e0 + e1);
        scores[r * 2 + 0] = e0 * inv;
        scores[r * 2 + 1] = e1 * inv;
    }
}

// ---------------- sine position encoding (f32; threshold is 0.117) ------------
__global__ __launch_bounds__(256) void k_pos(float* __restrict__ pos)
{
    int l = blockIdx.x, t = threadIdx.x;
    for (int k = t; k < D_; k += 256) {
        int kk = (k < 384) ? k : k - 384;
        int m = kk >> 1;
        float coord = (k < 384) ? (float)(l / 24) : (float)(l % 24);
        float v = (coord + 1.0f) / 24.000001f * 6.28318530717958647692f;
        float tm = exp2f((float)m * (13.287712379549449f / 192.0f)); // 10000^(m/192)
        float a = v / tm;
        pos[(size_t)l * D_ + k] = (kk & 1) ? cosf(a) : sinf(a);
    }
}

// ---------------- threefry2x32 (jax key(42)) ----------------
__device__ inline void threefry2x32(uint32_t x0, uint32_t x1,
                                    uint32_t& o0, uint32_t& o1)
{
    const uint32_t ks0 = 0u, ks1 = 42u;
    const uint32_t ks2 = ks0 ^ ks1 ^ 0x1BD11BDAu;
    uint32_t ks[3] = {ks0, ks1, ks2};
    x0 += ks[0]; x1 += ks[1];
    const int R0[4] = {13, 15, 26, 6};
    const int R1[4] = {17, 29, 16, 24};
    #pragma unroll
    for (int i = 0; i < 5; ++i) {
        const int* R = (i & 1) ? R1 : R0;
        #pragma unroll
        for (int q = 0; q < 4; ++q) {
            x0 += x1;
            x1 = (x1 << R[q]) | (x1 >> (32 - R[q]));
            x1 ^= x0;
        }
        x0 += ks[(i + 1) % 3];
        x1 += ks[(i + 2) % 3] + (uint32_t)(i + 1);
    }
    o0 = x0; o1 = x1;
}

// ---------------- top-10 + softmax + gumbel categorical, 16 rows ----------------
__global__ __launch_bounds__(256) void k_topk_sample(
    const float* __restrict__ d2row, const unsigned long long* __restrict__ amin,
    const int* __restrict__ mask, int* __restrict__ mlabel, int* __restrict__ negsel)
{
    __shared__ float sd2[KCODE];
    __shared__ unsigned long long rbuf[256];
    __shared__ float rfs[256];
    __shared__ int sel[TOPK];
    __shared__ float selv[TOPK];
    __shared__ float sS;
    int b = blockIdx.x, t = threadIdx.x;
    for (int j = t; j < KCODE; j += 256) sd2[j] = d2row[b * KCODE + j];
    __syncthreads();
    for (int p = 0; p < TOPK; ++p) {
        unsigned long long best = ~0ull;
        for (int j = t; j < KCODE; j += 256) {
            bool skip = false;
            for (int q = 0; q < p; ++q) skip = skip || (j == sel[q]);
            if (skip) continue;
            unsigned long long key =
                ((unsigned long long)__float_as_uint(sd2[j]) << 32) | (unsigned)j;
            best = umin64(best, key);
        }
        rbuf[t] = best;
        __syncthreads();
        for (int s = 128; s > 0; s >>= 1) {
            if (t < s) rbuf[t] = umin64(rbuf[t], rbuf[t + s]);
            __syncthreads();
        }
        if (t == 0) {
            sel[p] = (int)(rbuf[0] & 0xFFFFFFFFull);
            selv[p] = __uint_as_float((uint32_t)(rbuf[0] >> 32));
        }
        __syncthreads();
    }
    float d2min = selv[0];
    float part = 0.0f;
    for (int j = t; j < KCODE; j += 256) part += expf(d2min - sd2[j]);
    part = block_sum(part, rfs);
    if (t == 0) sS = part;
    __syncthreads();
    if (t == 0) {
        int rb = b * 576 + mask[b];
        mlabel[b] = (int)(amin[rb] & 0xFFFFFFFFull);
        float S = sS;
        float bestv = 0.0f;
        int samp = 0;
        bool first = true;
        for (int k = 0; k < TOPK; ++k) {
            float pk = expf(d2min - selv[k]) / S;
            float logit = logf(pk);
            unsigned f = (unsigned)(rb * 10 + k);
            uint32_t o0, o1;
            threefry2x32(0u, f, o0, o1);
            uint32_t bits = o0 ^ o1;
            float uu = __uint_as_float(0x3F800000u | (bits >> 9)) - 1.0f;
            uu = uu + 1.1754944e-38f;
            uu = fmaxf(1.1754944e-38f, uu);
            float gum = -logf(-logf(uu));
            float sc = logit + gum;
            if (first || sc > bestv) { bestv = sc; samp = k; first = false; }
        }
        negsel[b] = sel[samp];
    }
}

// ---------------- final: gate-mix, +pos, two LayerNorms ----------------
__global__ __launch_bounds__(256) void k_final(
    const float* __restrict__ embpt, const float* __restrict__ xq,
    const float* __restrict__ scores, const int* __restrict__ idx,
    const int* __restrict__ mlabel, const int* __restrict__ negsel,
    const float* __restrict__ E, const float* __restrict__ pos,
    const float* __restrict__ ow, const float* __restrict__ ob,
    float* __restrict__ outp, float* __restrict__ outn)
{
    __shared__ float red[256];
    int r = blockIdx.x, t = threadIdx.x;
    int b = r / 576, l = r % 576;
    float s0 = scores[r * 2 + 0], s1 = scores[r * 2 + 1];
    int ir = idx[r];
    int nidx = (ir == mlabel[b]) ? negsel[b] : ir;
    const float* ep = embpt + (size_t)r * D_;
    const float* xr = xq + (size_t)r * D_;
    const float* er = E + (size_t)nidx * D_;
    const float* pr = pos + (size_t)l * D_;
    float vp[3], vn[3];
    #pragma unroll
    for (int q = 0; q < 3; ++q) {
        int k = t + q * 256;
        float xv = xr[k] * s1;
        float pv = pr[k];
        vp[q] = (ep[k] * s0 + xv) + pv;
        vn[q] = (er[k] * s0 + xv) + pv;
    }
    float mup = block_sum(vp[0] + vp[1] + vp[2], red) * (1.0f / 768.0f);
    float a0 = vp[0] - mup, a1 = vp[1] - mup, a2 = vp[2] - mup;
    float varp = block_sum(a0 * a0 + a1 * a1 + a2 * a2, red) * (1.0f / 768.0f);
    float rnp = 1.0f / sqrtf(varp + 1e-5f);
    float mun = block_sum(vn[0] + vn[1] + vn[2], red) * (1.0f / 768.0f);
    float c0 = vn[0] - mun, c1 = vn[1] - mun, c2 = vn[2] - mun;
    float varn = block_sum(c0 * c0 + c1 * c1 + c2 * c2, red) * (1.0f / 768.0f);
    float rnn = 1.0f / sqrtf(varn + 1e-5f);
    float* op = outp + (size_t)r * D_;
    float* on = outn + (size_t)r * D_;
    op[t]       = a0 * rnp * ow[t]       + ob[t];
    op[t + 256] = a1 * rnp * ow[t + 256] + ob[t + 256];
    op[t + 512] = a2 * rnp * ow[t + 512] + ob[t + 512];
    on[t]       = c0 * rnn * ow[t]       + ob[t];
    on[t + 256] = c1 * rnn * ow[t + 256] + ob[t + 256];
    on[t + 512] = c2 * rnn * ow[t + 512] + ob[t + 512];
}

// ---------------- launcher ----------------
extern "C" void kernel_launch(void* const* d_in, const int* in_sizes, int n_in,
                              void* d_out, int out_size, void* d_ws, size_t ws_size,
                              hipStream_t stream)
{
    (void)in_sizes; (void)n_in; (void)out_size; (void)ws_size;
    const float* img    = (const float*)d_in[0];
    const int*   maski  = (const int*)d_in[1];
    const float* lin_w  = (const float*)d_in[2];
    const float* lin_b  = (const float*)d_in[3];
    const float* ln1_w  = (const float*)d_in[4];
    const float* ln1_b  = (const float*)d_in[5];
    const float* embed  = (const float*)d_in[6];
    const float* pos_w  = (const float*)d_in[7];
    const float* pos_b  = (const float*)d_in[8];
    const float* gate_w = (const float*)d_in[9];
    const float* gate_b = (const float*)d_in[10];
    const float* glnw   = (const float*)d_in[11];
    const float* glnb   = (const float*)d_in[12];
    const float* olnw   = (const float*)d_in[13];
    const float* olnb   = (const float*)d_in[14];

    uint8_t* wp = (uint8_t*)d_ws;
    auto alloc = [&](size_t bytes) -> void* {
        void* p = (void*)wp;
        wp += (bytes + 255) & ~(size_t)255;
        return p;
    };
    float* bufA = (float*)alloc((size_t)M_TOT * D_ * 4);   // gemm1 out, later emb_pt
    float* xq   = (float*)alloc((size_t)M_TOT * D_ * 4);
    float* xsq  = (float*)alloc((size_t)M_TOT * 4);
    float* esq  = (float*)alloc((size_t)KCODE * 4);
    unsigned long long* amin = (unsigned long long*)alloc((size_t)M_TOT * 8);
    int*   idxA   = (int*)alloc((size_t)M_TOT * 4);
    int*   rowflag = (int*)alloc((size_t)M_TOT * 4);
    float* scores = (float*)alloc((size_t)M_TOT * 2 * 4);
    float* posb   = (float*)alloc((size_t)576 * D_ * 4);
    float* d2row  = (float*)alloc((size_t)16 * KCODE * 4);
    int*   mlab   = (int*)alloc(16 * 4);
    int*   negsel = (int*)alloc(16 * 4);
    u16* Wh = (u16*)alloc((size_t)D_ * CIN_ * 2);
    u16* Wm = (u16*)alloc((size_t)D_ * CIN_ * 2);
    u16* Wl = (u16*)alloc((size_t)D_ * CIN_ * 2);
    u16* Ph = (u16*)alloc((size_t)D_ * D_ * 2);
    u16* Pl = (u16*)alloc((size_t)D_ * D_ * 2);
    // R region: img 3-way splits (dead after gemm1), then reused for X/E splits
    u16* R  = (u16*)alloc((size_t)3 * M_TOT * CIN_ * 2);
    u16* Ih = R;
    u16* Im = R + (size_t)M_TOT * CIN_;
    u16* Il = R + (size_t)2 * M_TOT * CIN_;
    u16* Xh = R;
    u16* Xl = Xh + (size_t)M_TOT * D_;
    u16* Eh = Xl + (size_t)M_TOT * D_;
    u16* El = Eh + (size_t)KCODE * D_;

    float* outp = (float*)d_out;
    float* outn = outp + (size_t)M_TOT * D_;

    hipMemsetAsync(amin, 0xFF, M_TOT * sizeof(unsigned long long), stream);

    dim3 blk(256);
    // 0) splits + rowflag
    k_split3<<<2048, blk, 0, stream>>>(img, Ih, Im, Il, M_TOT * CIN_ / 4);
    k_split3<<<768, blk, 0, stream>>>(lin_w, Wh, Wm, Wl, D_ * CIN_ / 4);
    k_split2<<<576, blk, 0, stream>>>(pos_w, Ph, Pl, D_ * D_ / 4);
    k_rowflag<<<M_TOT / 256, blk, 0, stream>>>(maski, rowflag);
    // 1) xq_pre = img @ lin_w^T + lin_b   (3-way split, 6-term MFMA, swizzled)
    k_gemm1_mfma<<<dim3(D_ / 128, M_TOT / 128), blk, 0, stream>>>(
        Ih, Im, Il, Wh, Wm, Wl, lin_b, bufA);
    // 2) xq = relu(LN(xq_pre)); xsq; bf16 split  (overwrites Ih/Im region)
    k_ln_relu<<<M_TOT, blk, 0, stream>>>(bufA, ln1_w, ln1_b, xq, xsq, Xh, Xl);
    // 3) esq + bf16 split
    k_esq<<<KCODE, blk, 0, stream>>>(embed, esq, Eh, El);
    // 4) fused code-search MFMA GEMM + argmin + masked-row d2 capture (dbuf)
    k_gemm2_mfma<<<dim3(KCODE / 128, M_TOT / 128), blk, 0, stream>>>(
        Xh, Xl, Eh, El, xsq, esq, rowflag, d2row, amin);
    // 5) idx
    k_extract<<<M_TOT / 256, blk, 0, stream>>>(amin, idxA, M_TOT);
    // 6) emb_pt = embed[idx] @ pos_w^T + pos_b  (2-way split, dbuf, gathered A)
    k_gemm3_mfma<<<dim3(D_ / 128, M_TOT / 128), blk, 0, stream>>>(
        Eh, El, Ph, Pl, idxA, pos_b, bufA);
    // 7) gate scores
    k_gate<<<M_TOT, blk, 0, stream>>>(bufA, xq, gate_w, gate_b, glnw, glnb, scores);
    // 8) positional encoding
    k_pos<<<576, blk, 0, stream>>>(posb);
    // 9) top-10 + threefry gumbel categorical (d2row from gemm2 epilogue)
    k_topk_sample<<<16, blk, 0, stream>>>(d2row, amin, maski, mlab, negsel);
    // 10) final mix + LN x2
    k_final<<<M_TOT, blk, 0, stream>>>(bufA, xq, scores, idxA, mlab, negsel,
                                       embed, posb, olnw, olnb, outp, outn);
}

// Round 10
// 757.773 us; speedup vs baseline: 1.0440x; 1.0440x over previous
//
#include <hip/hip_runtime.h>
#include <stdint.h>

#define M_TOT  9216   // 16*576
#define D_     768
#define CIN_   1024
#define KCODE  8192
#define TOPK   10

typedef unsigned short u16;
typedef __bf16 bf16x8 __attribute__((ext_vector_type(8)));
typedef float f32x4 __attribute__((ext_vector_type(4)));

// ---------------- helpers ----------------

__device__ inline float block_sum(float v, float* red) {
    int t = threadIdx.x;
    red[t] = v;
    __syncthreads();
    #pragma unroll
    for (int s = 128; s > 0; s >>= 1) {
        if (t < s) red[t] += red[t + s];
        __syncthreads();
    }
    float r = red[0];
    __syncthreads();
    return r;
}

__device__ inline unsigned long long umin64(unsigned long long a, unsigned long long b) {
    return (a < b) ? a : b;
}

__device__ inline u16 f2bf(float f) {          // RNE f32 -> bf16
    uint32_t u = __float_as_uint(f);
    uint32_t r = (u + 0x7fffu + ((u >> 16) & 1u)) >> 16;
    return (u16)r;
}
__device__ inline float bf2f(u16 h) {
    return __uint_as_float(((uint32_t)h) << 16);
}

__device__ inline unsigned long long shfl_xor_u64(unsigned long long v, int mask) {
    int lo = (int)(uint32_t)v, hi = (int)(uint32_t)(v >> 32);
    lo = __shfl_xor(lo, mask, 64);
    hi = __shfl_xor(hi, mask, 64);
    return ((unsigned long long)(uint32_t)hi << 32) | (uint32_t)lo;
}

#define GLDS(gp, lp) __builtin_amdgcn_global_load_lds( \
    (const __attribute__((address_space(1))) unsigned int*)(gp), \
    (__attribute__((address_space(3))) unsigned int*)(lp), 16, 0, 0)

// ---------------- GEMM1: 3-way-split bf16 MFMA, 6 terms, BK=32 swizzled -------
// BK=32 swizzle: slot = kb ^ ((r16>>1)&3); staging source k-chunk
// (lane&3)^((lane>>3)&3) of row c*16+(lane>>2). 2-way bank aliasing (free).
__global__ __launch_bounds__(256) void k_gemm1_mfma(
    const u16* __restrict__ Ah, const u16* __restrict__ Am, const u16* __restrict__ Al,
    const u16* __restrict__ Bh, const u16* __restrict__ Bm, const u16* __restrict__ Bl,
    const float* __restrict__ bias, float* __restrict__ C)
{
    __shared__ __align__(16) u16 sm[24576];   // 48KB: Ah|Am|Al|Bh|Bm|Bl, 4096 u16 each
    const int t = threadIdx.x;
    const int lane = t & 63, wid = t >> 6;
    const int row0 = blockIdx.y * 128, col0 = blockIdx.x * 128;
    const int r16 = lane & 15, kb = lane >> 4;
    const int wr = wid >> 1, wc = wid & 1;
    const int sc = (((lane & 3) ^ ((lane >> 3) & 3))) * 8;
    const int lrow = lane >> 2;
    const int swz = (r16 >> 1) & 3;

    f32x4 acc[4][4];
    #pragma unroll
    for (int mf = 0; mf < 4; ++mf)
        #pragma unroll
        for (int nf = 0; nf < 4; ++nf)
            acc[mf][nf] = (f32x4){0.f, 0.f, 0.f, 0.f};

    for (int k0 = 0; k0 < CIN_; k0 += 32) {
        __syncthreads();
        #pragma unroll
        for (int i = 0; i < 12; ++i) {
            int mat = i >> 1;
            int c = (i & 1) ? wid + 4 : wid;
            const u16* mp = (mat == 0) ? Ah : (mat == 1) ? Am : (mat == 2) ? Al
                          : (mat == 3) ? Bh : (mat == 4) ? Bm : Bl;
            int rbase = (mat < 3) ? row0 : col0;
            const u16* g = mp + (size_t)(rbase + c * 16 + lrow) * CIN_ + k0 + sc;
            GLDS(g, sm + mat * 4096 + c * 512);
        }
        __syncthreads();

        const int slot = (kb ^ swz) * 8;
        bf16x8 bh[4], bm[4], bl[4];
        #pragma unroll
        for (int nf = 0; nf < 4; ++nf) {
            int offb = 12288 + (wc * 64 + nf * 16 + r16) * 32 + slot;
            bh[nf] = *(const bf16x8*)(sm + offb);
            bm[nf] = *(const bf16x8*)(sm + offb + 4096);
            bl[nf] = *(const bf16x8*)(sm + offb + 8192);
        }
        #pragma unroll
        for (int mf = 0; mf < 4; ++mf) {
            int offa = (wr * 64 + mf * 16 + r16) * 32 + slot;
            bf16x8 ah = *(const bf16x8*)(sm + offa);
            bf16x8 am = *(const bf16x8*)(sm + offa + 4096);
            bf16x8 al = *(const bf16x8*)(sm + offa + 8192);
            #pragma unroll
            for (int nf = 0; nf < 4; ++nf) {
                acc[mf][nf] = __builtin_amdgcn_mfma_f32_16x16x32_bf16(ah, bh[nf], acc[mf][nf], 0, 0, 0);
                acc[mf][nf] = __builtin_amdgcn_mfma_f32_16x16x32_bf16(ah, bm[nf], acc[mf][nf], 0, 0, 0);
                acc[mf][nf] = __builtin_amdgcn_mfma_f32_16x16x32_bf16(am, bh[nf], acc[mf][nf], 0, 0, 0);
                acc[mf][nf] = __builtin_amdgcn_mfma_f32_16x16x32_bf16(am, bm[nf], acc[mf][nf], 0, 0, 0);
                acc[mf][nf] = __builtin_amdgcn_mfma_f32_16x16x32_bf16(ah, bl[nf], acc[mf][nf], 0, 0, 0);
                acc[mf][nf] = __builtin_amdgcn_mfma_f32_16x16x32_bf16(al, bh[nf], acc[mf][nf], 0, 0, 0);
            }
        }
    }

    #pragma unroll
    for (int mf = 0; mf < 4; ++mf) {
        #pragma unroll
        for (int q = 0; q < 4; ++q) {
            int m = row0 + wr * 64 + mf * 16 + kb * 4 + q;
            #pragma unroll
            for (int nf = 0; nf < 4; ++nf) {
                int n = col0 + wc * 64 + nf * 16 + r16;
                C[(size_t)m * D_ + n] = acc[mf][nf][q] + bias[n];
            }
        }
    }
}

// ---------------- GEMM3: 2-way-split MFMA, BK=32 swizzled dbuf, A gathered ----
__global__ __launch_bounds__(256) void k_gemm3_mfma(
    const u16* __restrict__ Eh, const u16* __restrict__ El,
    const u16* __restrict__ Ph, const u16* __restrict__ Pl,
    const int* __restrict__ gather,
    const float* __restrict__ bias, float* __restrict__ C)
{
    __shared__ __align__(16) u16 sm[2][16384];   // 2 x 32KB: Ah|Al|Bh|Bl
    const int t = threadIdx.x;
    const int lane = t & 63, wid = t >> 6;
    const int row0 = blockIdx.y * 128, col0 = blockIdx.x * 128;
    const int r16 = lane & 15, kb = lane >> 4;
    const int wr = wid >> 1, wc = wid & 1;
    const int sc = (((lane & 3) ^ ((lane >> 3) & 3))) * 8;
    const int lrow = lane >> 2;
    const int swz = (r16 >> 1) & 3;

    const u16* sb = (wid == 0) ? Eh : (wid == 1) ? El : (wid == 2) ? Ph : Pl;
    int grow[8];
    #pragma unroll
    for (int c = 0; c < 8; ++c) {
        int r = ((wid < 2) ? row0 : col0) + c * 16 + lrow;
        grow[c] = (wid < 2) ? gather[r] : r;
    }

    f32x4 acc[4][4];
    #pragma unroll
    for (int mf = 0; mf < 4; ++mf)
        #pragma unroll
        for (int nf = 0; nf < 4; ++nf)
            acc[mf][nf] = (f32x4){0.f, 0.f, 0.f, 0.f};

    auto STAGE = [&](int buf, int k0) {
        u16* dst = sm[buf] + wid * 4096 + lane * 8;
        #pragma unroll
        for (int c = 0; c < 8; ++c)
            GLDS(sb + (size_t)grow[c] * D_ + k0 + sc, dst + c * 512);
    };

    STAGE(0, 0);
    __syncthreads();
    for (int kt = 0; kt < 24; ++kt) {
        int cur = kt & 1;
        if (kt < 23) STAGE(cur ^ 1, (kt + 1) * 32);
        const u16* B = sm[cur];
        const int slot = (kb ^ swz) * 8;
        bf16x8 bh[4], bl[4];
        #pragma unroll
        for (int nf = 0; nf < 4; ++nf) {
            int off = 8192 + (wc * 64 + nf * 16 + r16) * 32 + slot;
            bh[nf] = *(const bf16x8*)(B + off);
            bl[nf] = *(const bf16x8*)(B + off + 4096);
        }
        #pragma unroll
        for (int mf = 0; mf < 4; ++mf) {
            int off = (wr * 64 + mf * 16 + r16) * 32 + slot;
            bf16x8 ah = *(const bf16x8*)(B + off);
            bf16x8 al = *(const bf16x8*)(B + off + 4096);
            #pragma unroll
            for (int nf = 0; nf < 4; ++nf) {
                acc[mf][nf] = __builtin_amdgcn_mfma_f32_16x16x32_bf16(ah, bh[nf], acc[mf][nf], 0, 0, 0);
                acc[mf][nf] = __builtin_amdgcn_mfma_f32_16x16x32_bf16(ah, bl[nf], acc[mf][nf], 0, 0, 0);
                acc[mf][nf] = __builtin_amdgcn_mfma_f32_16x16x32_bf16(al, bh[nf], acc[mf][nf], 0, 0, 0);
            }
        }
        __syncthreads();
    }

    #pragma unroll
    for (int mf = 0; mf < 4; ++mf) {
        #pragma unroll
        for (int q = 0; q < 4; ++q) {
            int m = row0 + wr * 64 + mf * 16 + kb * 4 + q;
            #pragma unroll
            for (int nf = 0; nf < 4; ++nf) {
                int n = col0 + wc * 64 + nf * 16 + r16;
                C[(size_t)m * D_ + n] = acc[mf][nf][q] + bias[n];
            }
        }
    }
}

// ---------------- GEMM2: round-8 verified form — BK=64 XOR-swizzled, sbuf -----
// 380us, MfmaUtil ~41%, 0 conflicts, 2 blocks/CU. Fused d2 + argmin + masked-
// row d2 capture. LDS per matrix: 128 rows x 64 u16; staging linear dest with
// inverse-swizzled per-lane source; reads slot=(h*4+kb)^(r16&7).
__global__ __launch_bounds__(256) void k_gemm2_mfma(
    const u16* __restrict__ Xh, const u16* __restrict__ Xl,
    const u16* __restrict__ Eh, const u16* __restrict__ El,
    const float* __restrict__ xsq, const float* __restrict__ esq,
    const int* __restrict__ rowflag, float* __restrict__ d2row,
    unsigned long long* __restrict__ amin)
{
    __shared__ __align__(16) u16 sm[32768];   // 64KB: Ah|Al|Bh|Bl each 8192 u16
    const int t = threadIdx.x;
    const int lane = t & 63, wid = t >> 6;
    const int row0 = blockIdx.y * 128, col0 = blockIdx.x * 128;
    const int r16 = lane & 15, kb = lane >> 4;
    const int wr = wid >> 1, wc = wid & 1;

    f32x4 acc[4][4];
    #pragma unroll
    for (int mf = 0; mf < 4; ++mf)
        #pragma unroll
        for (int nf = 0; nf < 4; ++nf)
            acc[mf][nf] = (f32x4){0.f, 0.f, 0.f, 0.f};

    const u16* sb = (wid == 0) ? Xh : (wid == 1) ? Xl : (wid == 2) ? Eh : El;
    const int rbase = (wid < 2) ? row0 : col0;
    // staging: lane l covers row rbase+(l>>3)+c*8, source k-chunk (l&7)^(l>>3)
    const u16* srcb = sb + (size_t)(rbase + (lane >> 3)) * D_
                         + ((lane & 7) ^ (lane >> 3)) * 8;
    u16* dstb = sm + wid * 8192 + lane * 8;

    const int swz = (r16 & 7);
    for (int kt = 0; kt < 12; ++kt) {
        __syncthreads();
        #pragma unroll
        for (int c = 0; c < 16; ++c) {
            GLDS(srcb + kt * 64 + c * 8 * D_, dstb + c * 512);
        }
        __syncthreads();
        #pragma unroll
        for (int h = 0; h < 2; ++h) {
            const int slot = ((h * 4 + kb) ^ swz) * 8;
            bf16x8 bh[4], bl[4];
            #pragma unroll
            for (int nf = 0; nf < 4; ++nf) {
                int off = (wc * 64 + nf * 16 + r16) * 64 + slot;
                bh[nf] = *(const bf16x8*)(sm + 16384 + off);
                bl[nf] = *(const bf16x8*)(sm + 24576 + off);
            }
            #pragma unroll
            for (int mf = 0; mf < 4; ++mf) {
                int off = (wr * 64 + mf * 16 + r16) * 64 + slot;
                bf16x8 ah = *(const bf16x8*)(sm + off);
                bf16x8 al = *(const bf16x8*)(sm + 8192 + off);
                #pragma unroll
                for (int nf = 0; nf < 4; ++nf) {
                    acc[mf][nf] = __builtin_amdgcn_mfma_f32_16x16x32_bf16(ah, bh[nf], acc[mf][nf], 0, 0, 0);
                    acc[mf][nf] = __builtin_amdgcn_mfma_f32_16x16x32_bf16(ah, bl[nf], acc[mf][nf], 0, 0, 0);
                    acc[mf][nf] = __builtin_amdgcn_mfma_f32_16x16x32_bf16(al, bh[nf], acc[mf][nf], 0, 0, 0);
                }
            }
        }
    }

    float esqv[4];
    #pragma unroll
    for (int nf = 0; nf < 4; ++nf)
        esqv[nf] = esq[col0 + wc * 64 + nf * 16 + r16];

    #pragma unroll
    for (int mf = 0; mf < 4; ++mf) {
        #pragma unroll
        for (int q = 0; q < 4; ++q) {
            int m = row0 + wr * 64 + mf * 16 + kb * 4 + q;
            float xsv = xsq[m];
            int rf = rowflag[m];
            unsigned long long best = ~0ull;
            #pragma unroll
            for (int nf = 0; nf < 4; ++nf) {
                int n = col0 + wc * 64 + nf * 16 + r16;
                float d2 = (xsv - 2.0f * acc[mf][nf][q]) + esqv[nf];
                if (rf) d2row[(size_t)(rf - 1) * KCODE + n] = d2;
                unsigned long long key =
                    ((unsigned long long)__float_as_uint(d2) << 32) | (unsigned)n;
                best = umin64(best, key);
            }
            #pragma unroll
            for (int msk = 1; msk < 16; msk <<= 1)
                best = umin64(best, shfl_xor_u64(best, msk));
            if (r16 == 0) atomicMin(&amin[m], best);
        }
    }
}

// ---------------- img split3 (grid-stride) ----------------
__global__ __launch_bounds__(256) void k_split3(const float* __restrict__ in,
    u16* __restrict__ h, u16* __restrict__ m, u16* __restrict__ l, int n4)
{
    int i = blockIdx.x * 256 + threadIdx.x;
    int stride = gridDim.x * 256;
    for (; i < n4; i += stride) {
        float4 v = ((const float4*)in)[i];
        ushort4 hv, mv, lv;
        float x, r;
        x = v.x; hv.x = f2bf(x); r = x - bf2f(hv.x); mv.x = f2bf(r); lv.x = f2bf(r - bf2f(mv.x));
        x = v.y; hv.y = f2bf(x); r = x - bf2f(hv.y); mv.y = f2bf(r); lv.y = f2bf(r - bf2f(mv.y));
        x = v.z; hv.z = f2bf(x); r = x - bf2f(hv.z); mv.z = f2bf(r); lv.z = f2bf(r - bf2f(mv.z));
        x = v.w; hv.w = f2bf(x); r = x - bf2f(hv.w); mv.w = f2bf(r); lv.w = f2bf(r - bf2f(mv.w));
        ((ushort4*)h)[i] = hv; ((ushort4*)m)[i] = mv; ((ushort4*)l)[i] = lv;
    }
}

// ---------------- merged prep: lin_w split3 | pos_w split2 | rowflag ----------
// grid = 768 + 576 + 36 = 1380 blocks; exact sizes, no loops.
__global__ __launch_bounds__(256) void k_prep(
    const float* __restrict__ lin_w, u16* __restrict__ Wh, u16* __restrict__ Wm,
    u16* __restrict__ Wl,
    const float* __restrict__ pos_w, u16* __restrict__ Ph, u16* __restrict__ Pl,
    const int* __restrict__ mask, int* __restrict__ rowflag)
{
    int bid = blockIdx.x;
    if (bid < 768) {
        int i = bid * 256 + threadIdx.x;          // n4 = 196608 = 768*256
        float4 v = ((const float4*)lin_w)[i];
        ushort4 hv, mv, lv;
        float x, r;
        x = v.x; hv.x = f2bf(x); r = x - bf2f(hv.x); mv.x = f2bf(r); lv.x = f2bf(r - bf2f(mv.x));
        x = v.y; hv.y = f2bf(x); r = x - bf2f(hv.y); mv.y = f2bf(r); lv.y = f2bf(r - bf2f(mv.y));
        x = v.z; hv.z = f2bf(x); r = x - bf2f(hv.z); mv.z = f2bf(r); lv.z = f2bf(r - bf2f(mv.z));
        x = v.w; hv.w = f2bf(x); r = x - bf2f(hv.w); mv.w = f2bf(r); lv.w = f2bf(r - bf2f(mv.w));
        ((ushort4*)Wh)[i] = hv; ((ushort4*)Wm)[i] = mv; ((ushort4*)Wl)[i] = lv;
    } else if (bid < 768 + 576) {
        int i = (bid - 768) * 256 + threadIdx.x;  // n4 = 147456 = 576*256
        float4 v = ((const float4*)pos_w)[i];
        ushort4 hv, lv;
        hv.x = f2bf(v.x); lv.x = f2bf(v.x - bf2f(hv.x));
        hv.y = f2bf(v.y); lv.y = f2bf(v.y - bf2f(hv.y));
        hv.z = f2bf(v.z); lv.z = f2bf(v.z - bf2f(hv.z));
        hv.w = f2bf(v.w); lv.w = f2bf(v.w - bf2f(hv.w));
        ((ushort4*)Ph)[i] = hv; ((ushort4*)Pl)[i] = lv;
    } else {
        int i = (bid - 1344) * 256 + threadIdx.x; // 9216 = 36*256
        int b = i / 576, l = i - b * 576;
        rowflag[i] = (mask[b] == l) ? (b + 1) : 0;
    }
}

// ---------------- LN1 + ReLU + row sum of squares + bf16 split ----------------
__global__ __launch_bounds__(256) void k_ln_relu(
    const float* __restrict__ in, const float* __restrict__ w,
    const float* __restrict__ b, float* __restrict__ xq, float* __restrict__ xsq,
    u16* __restrict__ Xh, u16* __restrict__ Xl)
{
    __shared__ float red[256];
    int r = blockIdx.x, t = threadIdx.x;
    const float* row = in + (size_t)r * D_;
    float v0 = row[t], v1 = row[t + 256], v2 = row[t + 512];
    float mu = block_sum(v0 + v1 + v2, red) * (1.0f / 768.0f);
    float d0 = v0 - mu, d1 = v1 - mu, d2 = v2 - mu;
    float var = block_sum(d0 * d0 + d1 * d1 + d2 * d2, red) * (1.0f / 768.0f);
    float rn = 1.0f / sqrtf(var + 1e-5f);
    float o0 = fmaxf(0.0f, d0 * rn * w[t] + b[t]);
    float o1 = fmaxf(0.0f, d1 * rn * w[t + 256] + b[t + 256]);
    float o2 = fmaxf(0.0f, d2 * rn * w[t + 512] + b[t + 512]);
    float* orow = xq + (size_t)r * D_;
    orow[t] = o0; orow[t + 256] = o1; orow[t + 512] = o2;
    u16 h0 = f2bf(o0), h1 = f2bf(o1), h2 = f2bf(o2);
    Xh[(size_t)r * D_ + t]       = h0;
    Xh[(size_t)r * D_ + t + 256] = h1;
    Xh[(size_t)r * D_ + t + 512] = h2;
    Xl[(size_t)r * D_ + t]       = f2bf(o0 - bf2f(h0));
    Xl[(size_t)r * D_ + t + 256] = f2bf(o1 - bf2f(h1));
    Xl[(size_t)r * D_ + t + 512] = f2bf(o2 - bf2f(h2));
    float q = block_sum(o0 * o0 + o1 * o1 + o2 * o2, red);
    if (t == 0) xsq[r] = q;
}

// ---------------- codebook row norms + bf16 split ----------------
__global__ __launch_bounds__(256) void k_esq(const float* __restrict__ E,
                                             float* __restrict__ esq,
                                             u16* __restrict__ Eh,
                                             u16* __restrict__ El)
{
    __shared__ float red[256];
    int r = blockIdx.x, t = threadIdx.x;
    const float* row = E + (size_t)r * D_;
    float v0 = row[t], v1 = row[t + 256], v2 = row[t + 512];
    u16 h0 = f2bf(v0), h1 = f2bf(v1), h2 = f2bf(v2);
    Eh[(size_t)r * D_ + t]       = h0;
    Eh[(size_t)r * D_ + t + 256] = h1;
    Eh[(size_t)r * D_ + t + 512] = h2;
    El[(size_t)r * D_ + t]       = f2bf(v0 - bf2f(h0));
    El[(size_t)r * D_ + t + 256] = f2bf(v1 - bf2f(h1));
    El[(size_t)r * D_ + t + 512] = f2bf(v2 - bf2f(h2));
    float s = block_sum(v0 * v0 + v1 * v1 + v2 * v2, red);
    if (t == 0) esq[r] = s;
}

__global__ void k_extract(const unsigned long long* __restrict__ amin,
                          int* __restrict__ idx, int n)
{
    int i = blockIdx.x * 256 + threadIdx.x;
    if (i < n) idx[i] = (int)(amin[i] & 0xFFFFFFFFull);
}

// ---------------- gate: 2-wide GEMV + LN(2) + relu + softmax ----------------
__global__ __launch_bounds__(256) void k_gate(
    const float* __restrict__ embpt, const float* __restrict__ xq,
    const float* __restrict__ gw, const float* __restrict__ gb,
    const float* __restrict__ glnw, const float* __restrict__ glnb,
    float* __restrict__ scores)
{
    __shared__ float red[256];
    int r = blockIdx.x, t = threadIdx.x;
    const float* ep = embpt + (size_t)r * D_;
    const float* xr = xq + (size_t)r * D_;
    float g0 = 0.0f, g1 = 0.0f;
    for (int k = t; k < 1536; k += 256) {
        float v = (k < 768) ? ep[k] : xr[k - 768];
        g0 = fmaf(v, gw[k], g0);
        g1 = fmaf(v, gw[1536 + k], g1);
    }
    g0 = block_sum(g0, red);
    g1 = block_sum(g1, red);
    if (t == 0) {
        g0 += gb[0]; g1 += gb[1];
        float mu = 0.5f * (g0 + g1);
        float h0 = g0 - mu, h1 = g1 - mu;
        float var = 0.5f * (h0 * h0 + h1 * h1);
        float rn = 1.0f / sqrtf(var + 1e-5f);
        float o0 = fmaxf(0.0f, h0 * rn * glnw[0] + glnb[0]);
        float o1 = fmaxf(0.0f, h1 * rn * glnw[1] + glnb[1]);
        float m = fmaxf(o0, o1);
        float e0 = expf(o0 - m), e1 = expf(o1 - m);
        float inv = 1.0f / (e0 + e1);
        scores[r * 2 + 0] = e0 * inv;
        scores[r * 2 + 1] = e1 * inv;
    }
}

// ---------------- sine position encoding (f32; threshold is 0.117) ------------
__global__ __launch_bounds__(256) void k_pos(float* __restrict__ pos)
{
    int l = blockIdx.x, t = threadIdx.x;
    for (int k = t; k < D_; k += 256) {
        int kk = (k < 384) ? k : k - 384;
        int m = kk >> 1;
        float coord = (k < 384) ? (float)(l / 24) : (float)(l % 24);
        float v = (coord + 1.0f) / 24.000001f * 6.28318530717958647692f;
        float tm = exp2f((float)m * (13.287712379549449f / 192.0f)); // 10000^(m/192)
        float a = v / tm;
        pos[(size_t)l * D_ + k] = (kk & 1) ? cosf(a) : sinf(a);
    }
}

// ---------------- threefry2x32 (jax key(42)) ----------------
__device__ inline void threefry2x32(uint32_t x0, uint32_t x1,
                                    uint32_t& o0, uint32_t& o1)
{
    const uint32_t ks0 = 0u, ks1 = 42u;
    const uint32_t ks2 = ks0 ^ ks1 ^ 0x1BD11BDAu;
    uint32_t ks[3] = {ks0, ks1, ks2};
    x0 += ks[0]; x1 += ks[1];
    const int R0[4] = {13, 15, 26, 6};
    const int R1[4] = {17, 29, 16, 24};
    #pragma unroll
    for (int i = 0; i < 5; ++i) {
        const int* R = (i & 1) ? R1 : R0;
        #pragma unroll
        for (int q = 0; q < 4; ++q) {
            x0 += x1;
            x1 = (x1 << R[q]) | (x1 >> (32 - R[q]));
            x1 ^= x0;
        }
        x0 += ks[(i + 1) % 3];
        x1 += ks[(i + 2) % 3] + (uint32_t)(i + 1);
    }
    o0 = x0; o1 = x1;
}

// ---------------- top-10 + softmax + gumbel categorical, 16 rows ----------------
__global__ __launch_bounds__(256) void k_topk_sample(
    const float* __restrict__ d2row, const unsigned long long* __restrict__ amin,
    const int* __restrict__ mask, int* __restrict__ mlabel, int* __restrict__ negsel)
{
    __shared__ float sd2[KCODE];
    __shared__ unsigned long long rbuf[256];
    __shared__ float rfs[256];
    __shared__ int sel[TOPK];
    __shared__ float selv[TOPK];
    __shared__ float sS;
    int b = blockIdx.x, t = threadIdx.x;
    for (int j = t; j < KCODE; j += 256) sd2[j] = d2row[b * KCODE + j];
    __syncthreads();
    for (int p = 0; p < TOPK; ++p) {
        unsigned long long best = ~0ull;
        for (int j = t; j < KCODE; j += 256) {
            bool skip = false;
            for (int q = 0; q < p; ++q) skip = skip || (j == sel[q]);
            if (skip) continue;
            unsigned long long key =
                ((unsigned long long)__float_as_uint(sd2[j]) << 32) | (unsigned)j;
            best = umin64(best, key);
        }
        rbuf[t] = best;
        __syncthreads();
        for (int s = 128; s > 0; s >>= 1) {
            if (t < s) rbuf[t] = umin64(rbuf[t], rbuf[t + s]);
            __syncthreads();
        }
        if (t == 0) {
            sel[p] = (int)(rbuf[0] & 0xFFFFFFFFull);
            selv[p] = __uint_as_float((uint32_t)(rbuf[0] >> 32));
        }
        __syncthreads();
    }
    float d2min = selv[0];
    float part = 0.0f;
    for (int j = t; j < KCODE; j += 256) part += expf(d2min - sd2[j]);
    part = block_sum(part, rfs);
    if (t == 0) sS = part;
    __syncthreads();
    if (t == 0) {
        int rb = b * 576 + mask[b];
        mlabel[b] = (int)(amin[rb] & 0xFFFFFFFFull);
        float S = sS;
        float bestv = 0.0f;
        int samp = 0;
        bool first = true;
        for (int k = 0; k < TOPK; ++k) {
            float pk = expf(d2min - selv[k]) / S;
            float logit = logf(pk);
            unsigned f = (unsigned)(rb * 10 + k);
            uint32_t o0, o1;
            threefry2x32(0u, f, o0, o1);
            uint32_t bits = o0 ^ o1;
            float uu = __uint_as_float(0x3F800000u | (bits >> 9)) - 1.0f;
            uu = uu + 1.1754944e-38f;
            uu = fmaxf(1.1754944e-38f, uu);
            float gum = -logf(-logf(uu));
            float sc = logit + gum;
            if (first || sc > bestv) { bestv = sc; samp = k; first = false; }
        }
        negsel[b] = sel[samp];
    }
}

// ---------------- final: gate-mix, +pos, two LayerNorms ----------------
__global__ __launch_bounds__(256) void k_final(
    const float* __restrict__ embpt, const float* __restrict__ xq,
    const float* __restrict__ scores, const int* __restrict__ idx,
    const int* __restrict__ mlabel, const int* __restrict__ negsel,
    const float* __restrict__ E, const float* __restrict__ pos,
    const float* __restrict__ ow, const float* __restrict__ ob,
    float* __restrict__ outp, float* __restrict__ outn)
{
    __shared__ float red[256];
    int r = blockIdx.x, t = threadIdx.x;
    int b = r / 576, l = r % 576;
    float s0 = scores[r * 2 + 0], s1 = scores[r * 2 + 1];
    int ir = idx[r];
    int nidx = (ir == mlabel[b]) ? negsel[b] : ir;
    const float* ep = embpt + (size_t)r * D_;
    const float* xr = xq + (size_t)r * D_;
    const float* er = E + (size_t)nidx * D_;
    const float* pr = pos + (size_t)l * D_;
    float vp[3], vn[3];
    #pragma unroll
    for (int q = 0; q < 3; ++q) {
        int k = t + q * 256;
        float xv = xr[k] * s1;
        float pv = pr[k];
        vp[q] = (ep[k] * s0 + xv) + pv;
        vn[q] = (er[k] * s0 + xv) + pv;
    }
    float mup = block_sum(vp[0] + vp[1] + vp[2], red) * (1.0f / 768.0f);
    float a0 = vp[0] - mup, a1 = vp[1] - mup, a2 = vp[2] - mup;
    float varp = block_sum(a0 * a0 + a1 * a1 + a2 * a2, red) * (1.0f / 768.0f);
    float rnp = 1.0f / sqrtf(varp + 1e-5f);
    float mun = block_sum(vn[0] + vn[1] + vn[2], red) * (1.0f / 768.0f);
    float c0 = vn[0] - mun, c1 = vn[1] - mun, c2 = vn[2] - mun;
    float varn = block_sum(c0 * c0 + c1 * c1 + c2 * c2, red) * (1.0f / 768.0f);
    float rnn = 1.0f / sqrtf(varn + 1e-5f);
    float* op = outp + (size_t)r * D_;
    float* on = outn + (size_t)r * D_;
    op[t]       = a0 * rnp * ow[t]       + ob[t];
    op[t + 256] = a1 * rnp * ow[t + 256] + ob[t + 256];
    op[t + 512] = a2 * rnp * ow[t + 512] + ob[t + 512];
    on[t]       = c0 * rnn * ow[t]       + ob[t];
    on[t + 256] = c1 * rnn * ow[t + 256] + ob[t + 256];
    on[t + 512] = c2 * rnn * ow[t + 512] + ob[t + 512];
}

// ---------------- launcher ----------------
extern "C" void kernel_launch(void* const* d_in, const int* in_sizes, int n_in,
                              void* d_out, int out_size, void* d_ws, size_t ws_size,
                              hipStream_t stream)
{
    (void)in_sizes; (void)n_in; (void)out_size; (void)ws_size;
    const float* img    = (const float*)d_in[0];
    const int*   maski  = (const int*)d_in[1];
    const float* lin_w  = (const float*)d_in[2];
    const float* lin_b  = (const float*)d_in[3];
    const float* ln1_w  = (const float*)d_in[4];
    const float* ln1_b  = (const float*)d_in[5];
    const float* embed  = (const float*)d_in[6];
    const float* pos_w  = (const float*)d_in[7];
    const float* pos_b  = (const float*)d_in[8];
    const float* gate_w = (const float*)d_in[9];
    const float* gate_b = (const float*)d_in[10];
    const float* glnw   = (const float*)d_in[11];
    const float* glnb   = (const float*)d_in[12];
    const float* olnw   = (const float*)d_in[13];
    const float* olnb   = (const float*)d_in[14];

    uint8_t* wp = (uint8_t*)d_ws;
    auto alloc = [&](size_t bytes) -> void* {
        void* p = (void*)wp;
        wp += (bytes + 255) & ~(size_t)255;
        return p;
    };
    float* bufA = (float*)alloc((size_t)M_TOT * D_ * 4);   // gemm1 out, later emb_pt
    float* xq   = (float*)alloc((size_t)M_TOT * D_ * 4);
    float* xsq  = (float*)alloc((size_t)M_TOT * 4);
    float* esq  = (float*)alloc((size_t)KCODE * 4);
    unsigned long long* amin = (unsigned long long*)alloc((size_t)M_TOT * 8);
    int*   idxA   = (int*)alloc((size_t)M_TOT * 4);
    int*   rowflag = (int*)alloc((size_t)M_TOT * 4);
    float* scores = (float*)alloc((size_t)M_TOT * 2 * 4);
    float* posb   = (float*)alloc((size_t)576 * D_ * 4);
    float* d2row  = (float*)alloc((size_t)16 * KCODE * 4);
    int*   mlab   = (int*)alloc(16 * 4);
    int*   negsel = (int*)alloc(16 * 4);
    u16* Wh = (u16*)alloc((size_t)D_ * CIN_ * 2);
    u16* Wm = (u16*)alloc((size_t)D_ * CIN_ * 2);
    u16* Wl = (u16*)alloc((size_t)D_ * CIN_ * 2);
    u16* Ph = (u16*)alloc((size_t)D_ * D_ * 2);
    u16* Pl = (u16*)alloc((size_t)D_ * D_ * 2);
    // R region: img 3-way splits (dead after gemm1), then reused for X/E splits
    u16* R  = (u16*)alloc((size_t)3 * M_TOT * CIN_ * 2);
    u16* Ih = R;
    u16* Im = R + (size_t)M_TOT * CIN_;
    u16* Il = R + (size_t)2 * M_TOT * CIN_;
    u16* Xh = R;
    u16* Xl = Xh + (size_t)M_TOT * D_;
    u16* Eh = Xl + (size_t)M_TOT * D_;
    u16* El = Eh + (size_t)KCODE * D_;

    float* outp = (float*)d_out;
    float* outn = outp + (size_t)M_TOT * D_;

    hipMemsetAsync(amin, 0xFF, M_TOT * sizeof(unsigned long long), stream);

    dim3 blk(256);
    // 0) splits + prep (merged)
    k_split3<<<2048, blk, 0, stream>>>(img, Ih, Im, Il, M_TOT * CIN_ / 4);
    k_prep<<<1380, blk, 0, stream>>>(lin_w, Wh, Wm, Wl, pos_w, Ph, Pl, maski, rowflag);
    // 1) xq_pre = img @ lin_w^T + lin_b   (3-way split, 6-term MFMA, swizzled)
    k_gemm1_mfma<<<dim3(D_ / 128, M_TOT / 128), blk, 0, stream>>>(
        Ih, Im, Il, Wh, Wm, Wl, lin_b, bufA);
    // 2) xq = relu(LN(xq_pre)); xsq; bf16 split  (overwrites Ih/Im region)
    k_ln_relu<<<M_TOT, blk, 0, stream>>>(bufA, ln1_w, ln1_b, xq, xsq, Xh, Xl);
    // 3) esq + bf16 split
    k_esq<<<KCODE, blk, 0, stream>>>(embed, esq, Eh, El);
    // 4) fused code-search MFMA GEMM + argmin + masked-row d2 capture
    k_gemm2_mfma<<<dim3(KCODE / 128, M_TOT / 128), blk, 0, stream>>>(
        Xh, Xl, Eh, El, xsq, esq, rowflag, d2row, amin);
    // 5) idx
    k_extract<<<M_TOT / 256, blk, 0, stream>>>(amin, idxA, M_TOT);
    // 6) emb_pt = embed[idx] @ pos_w^T + pos_b  (2-way split, dbuf, gathered A)
    k_gemm3_mfma<<<dim3(D_ / 128, M_TOT / 128), blk, 0, stream>>>(
        Eh, El, Ph, Pl, idxA, pos_b, bufA);
    // 7) gate scores
    k_gate<<<M_TOT, blk, 0, stream>>>(bufA, xq, gate_w, gate_b, glnw, glnb, scores);
    // 8) positional encoding
    k_pos<<<576, blk, 0, stream>>>(posb);
    // 9) top-10 + threefry gumbel categorical (d2row from gemm2 epilogue)
    k_topk_sample<<<16, blk, 0, stream>>>(d2row, amin, maski, mlab, negsel);
    // 10) final mix + LN x2
    k_final<<<M_TOT, blk, 0, stream>>>(bufA, xq, scores, idxA, mlab, negsel,
                                       embed, posb, olnw, olnb, outp, outn);
}

// Round 11
// 747.332 us; speedup vs baseline: 1.0586x; 1.0140x over previous
//
#include <hip/hip_runtime.h>
#include <stdint.h>

#define M_TOT  9216   // 16*576
#define D_     768
#define CIN_   1024
#define KCODE  8192
#define TOPK   10

typedef unsigned short u16;
typedef __bf16 bf16x8 __attribute__((ext_vector_type(8)));
typedef float f32x4 __attribute__((ext_vector_type(4)));

// ---------------- helpers ----------------

__device__ inline float block_sum(float v, float* red) {
    int t = threadIdx.x;
    red[t] = v;
    __syncthreads();
    #pragma unroll
    for (int s = 128; s > 0; s >>= 1) {
        if (t < s) red[t] += red[t + s];
        __syncthreads();
    }
    float r = red[0];
    __syncthreads();
    return r;
}

__device__ inline unsigned long long umin64(unsigned long long a, unsigned long long b) {
    return (a < b) ? a : b;
}

__device__ inline u16 f2bf(float f) {          // RNE f32 -> bf16
    uint32_t u = __float_as_uint(f);
    uint32_t r = (u + 0x7fffu + ((u >> 16) & 1u)) >> 16;
    return (u16)r;
}
__device__ inline float bf2f(u16 h) {
    return __uint_as_float(((uint32_t)h) << 16);
}

__device__ inline unsigned long long shfl_xor_u64(unsigned long long v, int mask) {
    int lo = (int)(uint32_t)v, hi = (int)(uint32_t)(v >> 32);
    lo = __shfl_xor(lo, mask, 64);
    hi = __shfl_xor(hi, mask, 64);
    return ((unsigned long long)(uint32_t)hi << 32) | (uint32_t)lo;
}

#define GLDS(gp, lp) __builtin_amdgcn_global_load_lds( \
    (const __attribute__((address_space(1))) unsigned int*)(gp), \
    (__attribute__((address_space(3))) unsigned int*)(lp), 16, 0, 0)

// ---------------- GEMM1: 3-way-split bf16 MFMA, 6 terms, BK=32 swizzled -------
// BK=32 swizzle: slot = kb ^ ((r16>>1)&3); staging source k-chunk
// (lane&3)^((lane>>3)&3) of row c*16+(lane>>2). 2-way bank aliasing (free).
__global__ __launch_bounds__(256) void k_gemm1_mfma(
    const u16* __restrict__ Ah, const u16* __restrict__ Am, const u16* __restrict__ Al,
    const u16* __restrict__ Bh, const u16* __restrict__ Bm, const u16* __restrict__ Bl,
    const float* __restrict__ bias, float* __restrict__ C)
{
    __shared__ __align__(16) u16 sm[24576];   // 48KB: Ah|Am|Al|Bh|Bm|Bl, 4096 u16 each
    const int t = threadIdx.x;
    const int lane = t & 63, wid = t >> 6;
    const int row0 = blockIdx.y * 128, col0 = blockIdx.x * 128;
    const int r16 = lane & 15, kb = lane >> 4;
    const int wr = wid >> 1, wc = wid & 1;
    const int sc = (((lane & 3) ^ ((lane >> 3) & 3))) * 8;
    const int lrow = lane >> 2;
    const int swz = (r16 >> 1) & 3;

    f32x4 acc[4][4];
    #pragma unroll
    for (int mf = 0; mf < 4; ++mf)
        #pragma unroll
        for (int nf = 0; nf < 4; ++nf)
            acc[mf][nf] = (f32x4){0.f, 0.f, 0.f, 0.f};

    for (int k0 = 0; k0 < CIN_; k0 += 32) {
        __syncthreads();
        #pragma unroll
        for (int i = 0; i < 12; ++i) {
            int mat = i >> 1;
            int c = (i & 1) ? wid + 4 : wid;
            const u16* mp = (mat == 0) ? Ah : (mat == 1) ? Am : (mat == 2) ? Al
                          : (mat == 3) ? Bh : (mat == 4) ? Bm : Bl;
            int rbase = (mat < 3) ? row0 : col0;
            const u16* g = mp + (size_t)(rbase + c * 16 + lrow) * CIN_ + k0 + sc;
            GLDS(g, sm + mat * 4096 + c * 512);
        }
        __syncthreads();

        const int slot = (kb ^ swz) * 8;
        bf16x8 bh[4], bm[4], bl[4];
        #pragma unroll
        for (int nf = 0; nf < 4; ++nf) {
            int offb = 12288 + (wc * 64 + nf * 16 + r16) * 32 + slot;
            bh[nf] = *(const bf16x8*)(sm + offb);
            bm[nf] = *(const bf16x8*)(sm + offb + 4096);
            bl[nf] = *(const bf16x8*)(sm + offb + 8192);
        }
        #pragma unroll
        for (int mf = 0; mf < 4; ++mf) {
            int offa = (wr * 64 + mf * 16 + r16) * 32 + slot;
            bf16x8 ah = *(const bf16x8*)(sm + offa);
            bf16x8 am = *(const bf16x8*)(sm + offa + 4096);
            bf16x8 al = *(const bf16x8*)(sm + offa + 8192);
            #pragma unroll
            for (int nf = 0; nf < 4; ++nf) {
                acc[mf][nf] = __builtin_amdgcn_mfma_f32_16x16x32_bf16(ah, bh[nf], acc[mf][nf], 0, 0, 0);
                acc[mf][nf] = __builtin_amdgcn_mfma_f32_16x16x32_bf16(ah, bm[nf], acc[mf][nf], 0, 0, 0);
                acc[mf][nf] = __builtin_amdgcn_mfma_f32_16x16x32_bf16(am, bh[nf], acc[mf][nf], 0, 0, 0);
                acc[mf][nf] = __builtin_amdgcn_mfma_f32_16x16x32_bf16(am, bm[nf], acc[mf][nf], 0, 0, 0);
                acc[mf][nf] = __builtin_amdgcn_mfma_f32_16x16x32_bf16(ah, bl[nf], acc[mf][nf], 0, 0, 0);
                acc[mf][nf] = __builtin_amdgcn_mfma_f32_16x16x32_bf16(al, bh[nf], acc[mf][nf], 0, 0, 0);
            }
        }
    }

    #pragma unroll
    for (int mf = 0; mf < 4; ++mf) {
        #pragma unroll
        for (int q = 0; q < 4; ++q) {
            int m = row0 + wr * 64 + mf * 16 + kb * 4 + q;
            #pragma unroll
            for (int nf = 0; nf < 4; ++nf) {
                int n = col0 + wc * 64 + nf * 16 + r16;
                C[(size_t)m * D_ + n] = acc[mf][nf][q] + bias[n];
            }
        }
    }
}

// ---------------- GEMM3: 2-way-split MFMA, BK=32 swizzled dbuf, A via amin ----
__global__ __launch_bounds__(256) void k_gemm3_mfma(
    const u16* __restrict__ Eh, const u16* __restrict__ El,
    const u16* __restrict__ Ph, const u16* __restrict__ Pl,
    const unsigned long long* __restrict__ amin,
    const float* __restrict__ bias, float* __restrict__ C)
{
    __shared__ __align__(16) u16 sm[2][16384];   // 2 x 32KB: Ah|Al|Bh|Bl
    const int t = threadIdx.x;
    const int lane = t & 63, wid = t >> 6;
    const int row0 = blockIdx.y * 128, col0 = blockIdx.x * 128;
    const int r16 = lane & 15, kb = lane >> 4;
    const int wr = wid >> 1, wc = wid & 1;
    const int sc = (((lane & 3) ^ ((lane >> 3) & 3))) * 8;
    const int lrow = lane >> 2;
    const int swz = (r16 >> 1) & 3;

    const u16* sb = (wid == 0) ? Eh : (wid == 1) ? El : (wid == 2) ? Ph : Pl;
    int grow[8];
    #pragma unroll
    for (int c = 0; c < 8; ++c) {
        int r = ((wid < 2) ? row0 : col0) + c * 16 + lrow;
        grow[c] = (wid < 2) ? (int)(amin[r] & 0xFFFFFFFFull) : r;
    }

    f32x4 acc[4][4];
    #pragma unroll
    for (int mf = 0; mf < 4; ++mf)
        #pragma unroll
        for (int nf = 0; nf < 4; ++nf)
            acc[mf][nf] = (f32x4){0.f, 0.f, 0.f, 0.f};

    auto STAGE = [&](int buf, int k0) {
        u16* dst = sm[buf] + wid * 4096 + lane * 8;
        #pragma unroll
        for (int c = 0; c < 8; ++c)
            GLDS(sb + (size_t)grow[c] * D_ + k0 + sc, dst + c * 512);
    };

    STAGE(0, 0);
    __syncthreads();
    for (int kt = 0; kt < 24; ++kt) {
        int cur = kt & 1;
        if (kt < 23) STAGE(cur ^ 1, (kt + 1) * 32);
        const u16* B = sm[cur];
        const int slot = (kb ^ swz) * 8;
        bf16x8 bh[4], bl[4];
        #pragma unroll
        for (int nf = 0; nf < 4; ++nf) {
            int off = 8192 + (wc * 64 + nf * 16 + r16) * 32 + slot;
            bh[nf] = *(const bf16x8*)(B + off);
            bl[nf] = *(const bf16x8*)(B + off + 4096);
        }
        #pragma unroll
        for (int mf = 0; mf < 4; ++mf) {
            int off = (wr * 64 + mf * 16 + r16) * 32 + slot;
            bf16x8 ah = *(const bf16x8*)(B + off);
            bf16x8 al = *(const bf16x8*)(B + off + 4096);
            #pragma unroll
            for (int nf = 0; nf < 4; ++nf) {
                acc[mf][nf] = __builtin_amdgcn_mfma_f32_16x16x32_bf16(ah, bh[nf], acc[mf][nf], 0, 0, 0);
                acc[mf][nf] = __builtin_amdgcn_mfma_f32_16x16x32_bf16(ah, bl[nf], acc[mf][nf], 0, 0, 0);
                acc[mf][nf] = __builtin_amdgcn_mfma_f32_16x16x32_bf16(al, bh[nf], acc[mf][nf], 0, 0, 0);
            }
        }
        __syncthreads();
    }

    #pragma unroll
    for (int mf = 0; mf < 4; ++mf) {
        #pragma unroll
        for (int q = 0; q < 4; ++q) {
            int m = row0 + wr * 64 + mf * 16 + kb * 4 + q;
            #pragma unroll
            for (int nf = 0; nf < 4; ++nf) {
                int n = col0 + wc * 64 + nf * 16 + r16;
                C[(size_t)m * D_ + n] = acc[mf][nf][q] + bias[n];
            }
        }
    }
}

// ---------------- GEMM2: round-8 verified — BK=64 XOR-swizzled, sbuf ----------
// 380us, MfmaUtil ~41%, 0 conflicts, 2 blocks/CU. At the ~900TF 2-barrier
// structural ceiling (915 TF effective). Fused d2 + argmin + masked-row d2.
__global__ __launch_bounds__(256) void k_gemm2_mfma(
    const u16* __restrict__ Xh, const u16* __restrict__ Xl,
    const u16* __restrict__ Eh, const u16* __restrict__ El,
    const float* __restrict__ xsq, const float* __restrict__ esq,
    const int* __restrict__ rowflag, float* __restrict__ d2row,
    unsigned long long* __restrict__ amin)
{
    __shared__ __align__(16) u16 sm[32768];   // 64KB: Ah|Al|Bh|Bl each 8192 u16
    const int t = threadIdx.x;
    const int lane = t & 63, wid = t >> 6;
    const int row0 = blockIdx.y * 128, col0 = blockIdx.x * 128;
    const int r16 = lane & 15, kb = lane >> 4;
    const int wr = wid >> 1, wc = wid & 1;

    f32x4 acc[4][4];
    #pragma unroll
    for (int mf = 0; mf < 4; ++mf)
        #pragma unroll
        for (int nf = 0; nf < 4; ++nf)
            acc[mf][nf] = (f32x4){0.f, 0.f, 0.f, 0.f};

    const u16* sb = (wid == 0) ? Xh : (wid == 1) ? Xl : (wid == 2) ? Eh : El;
    const int rbase = (wid < 2) ? row0 : col0;
    // staging: lane l covers row rbase+(l>>3)+c*8, source k-chunk (l&7)^(l>>3)
    const u16* srcb = sb + (size_t)(rbase + (lane >> 3)) * D_
                         + ((lane & 7) ^ (lane >> 3)) * 8;
    u16* dstb = sm + wid * 8192 + lane * 8;

    const int swz = (r16 & 7);
    for (int kt = 0; kt < 12; ++kt) {
        __syncthreads();
        #pragma unroll
        for (int c = 0; c < 16; ++c) {
            GLDS(srcb + kt * 64 + c * 8 * D_, dstb + c * 512);
        }
        __syncthreads();
        #pragma unroll
        for (int h = 0; h < 2; ++h) {
            const int slot = ((h * 4 + kb) ^ swz) * 8;
            bf16x8 bh[4], bl[4];
            #pragma unroll
            for (int nf = 0; nf < 4; ++nf) {
                int off = (wc * 64 + nf * 16 + r16) * 64 + slot;
                bh[nf] = *(const bf16x8*)(sm + 16384 + off);
                bl[nf] = *(const bf16x8*)(sm + 24576 + off);
            }
            #pragma unroll
            for (int mf = 0; mf < 4; ++mf) {
                int off = (wr * 64 + mf * 16 + r16) * 64 + slot;
                bf16x8 ah = *(const bf16x8*)(sm + off);
                bf16x8 al = *(const bf16x8*)(sm + 8192 + off);
                #pragma unroll
                for (int nf = 0; nf < 4; ++nf) {
                    acc[mf][nf] = __builtin_amdgcn_mfma_f32_16x16x32_bf16(ah, bh[nf], acc[mf][nf], 0, 0, 0);
                    acc[mf][nf] = __builtin_amdgcn_mfma_f32_16x16x32_bf16(ah, bl[nf], acc[mf][nf], 0, 0, 0);
                    acc[mf][nf] = __builtin_amdgcn_mfma_f32_16x16x32_bf16(al, bh[nf], acc[mf][nf], 0, 0, 0);
                }
            }
        }
    }

    float esqv[4];
    #pragma unroll
    for (int nf = 0; nf < 4; ++nf)
        esqv[nf] = esq[col0 + wc * 64 + nf * 16 + r16];

    #pragma unroll
    for (int mf = 0; mf < 4; ++mf) {
        #pragma unroll
        for (int q = 0; q < 4; ++q) {
            int m = row0 + wr * 64 + mf * 16 + kb * 4 + q;
            float xsv = xsq[m];
            int rf = rowflag[m];
            unsigned long long best = ~0ull;
            #pragma unroll
            for (int nf = 0; nf < 4; ++nf) {
                int n = col0 + wc * 64 + nf * 16 + r16;
                float d2 = (xsv - 2.0f * acc[mf][nf][q]) + esqv[nf];
                if (rf) d2row[(size_t)(rf - 1) * KCODE + n] = d2;
                unsigned long long key =
                    ((unsigned long long)__float_as_uint(d2) << 32) | (unsigned)n;
                best = umin64(best, key);
            }
            #pragma unroll
            for (int msk = 1; msk < 16; msk <<= 1)
                best = umin64(best, shfl_xor_u64(best, msk));
            if (r16 == 0) atomicMin(&amin[m], best);
        }
    }
}

// ---------------- merged prep (all input-only work, sectioned grid) -----------
// [0,9216): img split3 | [9216,9984): lin_w split3 | [9984,10560): pos_w split2
// [10560,11136): pos encoding | [11136,11172): rowflag.  All exact-size.
__global__ __launch_bounds__(256) void k_prep(
    const float* __restrict__ img, u16* __restrict__ Ih, u16* __restrict__ Im,
    u16* __restrict__ Il,
    const float* __restrict__ lin_w, u16* __restrict__ Wh, u16* __restrict__ Wm,
    u16* __restrict__ Wl,
    const float* __restrict__ pos_w, u16* __restrict__ Ph, u16* __restrict__ Pl,
    float* __restrict__ pos,
    const int* __restrict__ mask, int* __restrict__ rowflag)
{
    int bid = blockIdx.x, t = threadIdx.x;
    if (bid < 9216) {
        int i = bid * 256 + t;                    // n4 = 2359296 = 9216*256
        float4 v = ((const float4*)img)[i];
        ushort4 hv, mv, lv;
        float x, r;
        x = v.x; hv.x = f2bf(x); r = x - bf2f(hv.x); mv.x = f2bf(r); lv.x = f2bf(r - bf2f(mv.x));
        x = v.y; hv.y = f2bf(x); r = x - bf2f(hv.y); mv.y = f2bf(r); lv.y = f2bf(r - bf2f(mv.y));
        x = v.z; hv.z = f2bf(x); r = x - bf2f(hv.z); mv.z = f2bf(r); lv.z = f2bf(r - bf2f(mv.z));
        x = v.w; hv.w = f2bf(x); r = x - bf2f(hv.w); mv.w = f2bf(r); lv.w = f2bf(r - bf2f(mv.w));
        ((ushort4*)Ih)[i] = hv; ((ushort4*)Im)[i] = mv; ((ushort4*)Il)[i] = lv;
    } else if (bid < 9984) {
        int i = (bid - 9216) * 256 + t;           // n4 = 196608 = 768*256
        float4 v = ((const float4*)lin_w)[i];
        ushort4 hv, mv, lv;
        float x, r;
        x = v.x; hv.x = f2bf(x); r = x - bf2f(hv.x); mv.x = f2bf(r); lv.x = f2bf(r - bf2f(mv.x));
        x = v.y; hv.y = f2bf(x); r = x - bf2f(hv.y); mv.y = f2bf(r); lv.y = f2bf(r - bf2f(mv.y));
        x = v.z; hv.z = f2bf(x); r = x - bf2f(hv.z); mv.z = f2bf(r); lv.z = f2bf(r - bf2f(mv.z));
        x = v.w; hv.w = f2bf(x); r = x - bf2f(hv.w); mv.w = f2bf(r); lv.w = f2bf(r - bf2f(mv.w));
        ((ushort4*)Wh)[i] = hv; ((ushort4*)Wm)[i] = mv; ((ushort4*)Wl)[i] = lv;
    } else if (bid < 10560) {
        int i = (bid - 9984) * 256 + t;           // n4 = 147456 = 576*256
        float4 v = ((const float4*)pos_w)[i];
        ushort4 hv, lv;
        hv.x = f2bf(v.x); lv.x = f2bf(v.x - bf2f(hv.x));
        hv.y = f2bf(v.y); lv.y = f2bf(v.y - bf2f(hv.y));
        hv.z = f2bf(v.z); lv.z = f2bf(v.z - bf2f(hv.z));
        hv.w = f2bf(v.w); lv.w = f2bf(v.w - bf2f(hv.w));
        ((ushort4*)Ph)[i] = hv; ((ushort4*)Pl)[i] = lv;
    } else if (bid < 11136) {
        int l = bid - 10560;                      // 576 rows
        for (int k = t; k < D_; k += 256) {
            int kk = (k < 384) ? k : k - 384;
            int m = kk >> 1;
            float coord = (k < 384) ? (float)(l / 24) : (float)(l % 24);
            float v = (coord + 1.0f) / 24.000001f * 6.28318530717958647692f;
            float tm = exp2f((float)m * (13.287712379549449f / 192.0f)); // 10000^(m/192)
            float a = v / tm;
            pos[(size_t)l * D_ + k] = (kk & 1) ? cosf(a) : sinf(a);
        }
    } else {
        int i = (bid - 11136) * 256 + t;          // 9216 = 36*256
        int b = i / 576, l = i - b * 576;
        rowflag[i] = (mask[b] == l) ? (b + 1) : 0;
    }
}

// ---------------- merged: LN1+ReLU+xsq+X-split  |  esq+E-split ----------------
// [0,9216): ln_relu row r=bid  |  [9216,17408): esq row r=bid-9216.
__global__ __launch_bounds__(256) void k_ln_esq(
    const float* __restrict__ in, const float* __restrict__ w,
    const float* __restrict__ b, float* __restrict__ xq, float* __restrict__ xsq,
    u16* __restrict__ Xh, u16* __restrict__ Xl,
    const float* __restrict__ E, float* __restrict__ esq,
    u16* __restrict__ Eh, u16* __restrict__ El)
{
    __shared__ float red[256];
    int t = threadIdx.x;
    if (blockIdx.x < 9216) {
        int r = blockIdx.x;
        const float* row = in + (size_t)r * D_;
        float v0 = row[t], v1 = row[t + 256], v2 = row[t + 512];
        float mu = block_sum(v0 + v1 + v2, red) * (1.0f / 768.0f);
        float d0 = v0 - mu, d1 = v1 - mu, d2 = v2 - mu;
        float var = block_sum(d0 * d0 + d1 * d1 + d2 * d2, red) * (1.0f / 768.0f);
        float rn = 1.0f / sqrtf(var + 1e-5f);
        float o0 = fmaxf(0.0f, d0 * rn * w[t] + b[t]);
        float o1 = fmaxf(0.0f, d1 * rn * w[t + 256] + b[t + 256]);
        float o2 = fmaxf(0.0f, d2 * rn * w[t + 512] + b[t + 512]);
        float* orow = xq + (size_t)r * D_;
        orow[t] = o0; orow[t + 256] = o1; orow[t + 512] = o2;
        u16 h0 = f2bf(o0), h1 = f2bf(o1), h2 = f2bf(o2);
        Xh[(size_t)r * D_ + t]       = h0;
        Xh[(size_t)r * D_ + t + 256] = h1;
        Xh[(size_t)r * D_ + t + 512] = h2;
        Xl[(size_t)r * D_ + t]       = f2bf(o0 - bf2f(h0));
        Xl[(size_t)r * D_ + t + 256] = f2bf(o1 - bf2f(h1));
        Xl[(size_t)r * D_ + t + 512] = f2bf(o2 - bf2f(h2));
        float q = block_sum(o0 * o0 + o1 * o1 + o2 * o2, red);
        if (t == 0) xsq[r] = q;
    } else {
        int r = blockIdx.x - 9216;
        const float* row = E + (size_t)r * D_;
        float v0 = row[t], v1 = row[t + 256], v2 = row[t + 512];
        u16 h0 = f2bf(v0), h1 = f2bf(v1), h2 = f2bf(v2);
        Eh[(size_t)r * D_ + t]       = h0;
        Eh[(size_t)r * D_ + t + 256] = h1;
        Eh[(size_t)r * D_ + t + 512] = h2;
        El[(size_t)r * D_ + t]       = f2bf(v0 - bf2f(h0));
        El[(size_t)r * D_ + t + 256] = f2bf(v1 - bf2f(h1));
        El[(size_t)r * D_ + t + 512] = f2bf(v2 - bf2f(h2));
        float s = block_sum(v0 * v0 + v1 * v1 + v2 * v2, red);
        if (t == 0) esq[r] = s;
    }
}

// ---------------- gate: 2-wide GEMV + LN(2) + relu + softmax ----------------
__global__ __launch_bounds__(256) void k_gate(
    const float* __restrict__ embpt, const float* __restrict__ xq,
    const float* __restrict__ gw, const float* __restrict__ gb,
    const float* __restrict__ glnw, const float* __restrict__ glnb,
    float* __restrict__ scores)
{
    __shared__ float red[256];
    int r = blockIdx.x, t = threadIdx.x;
    const float* ep = embpt + (size_t)r * D_;
    const float* xr = xq + (size_t)r * D_;
    float g0 = 0.0f, g1 = 0.0f;
    for (int k = t; k < 1536; k += 256) {
        float v = (k < 768) ? ep[k] : xr[k - 768];
        g0 = fmaf(v, gw[k], g0);
        g1 = fmaf(v, gw[1536 + k], g1);
    }
    g0 = block_sum(g0, red);
    g1 = block_sum(g1, red);
    if (t == 0) {
        g0 += gb[0]; g1 += gb[1];
        float mu = 0.5f * (g0 + g1);
        float h0 = g0 - mu, h1 = g1 - mu;
        float var = 0.5f * (h0 * h0 + h1 * h1);
        float rn = 1.0f / sqrtf(var + 1e-5f);
        float o0 = fmaxf(0.0f, h0 * rn * glnw[0] + glnb[0]);
        float o1 = fmaxf(0.0f, h1 * rn * glnw[1] + glnb[1]);
        float m = fmaxf(o0, o1);
        float e0 = expf(o0 - m), e1 = expf(o1 - m);
        float inv = 1.0f / (e0 + e1);
        scores[r * 2 + 0] = e0 * inv;
        scores[r * 2 + 1] = e1 * inv;
    }
}

// ---------------- threefry2x32 (jax key(42)) ----------------
__device__ inline void threefry2x32(uint32_t x0, uint32_t x1,
                                    uint32_t& o0, uint32_t& o1)
{
    const uint32_t ks0 = 0u, ks1 = 42u;
    const uint32_t ks2 = ks0 ^ ks1 ^ 0x1BD11BDAu;
    uint32_t ks[3] = {ks0, ks1, ks2};
    x0 += ks[0]; x1 += ks[1];
    const int R0[4] = {13, 15, 26, 6};
    const int R1[4] = {17, 29, 16, 24};
    #pragma unroll
    for (int i = 0; i < 5; ++i) {
        const int* R = (i & 1) ? R1 : R0;
        #pragma unroll
        for (int q = 0; q < 4; ++q) {
            x0 += x1;
            x1 = (x1 << R[q]) | (x1 >> (32 - R[q]));
            x1 ^= x0;
        }
        x0 += ks[(i + 1) % 3];
        x1 += ks[(i + 2) % 3] + (uint32_t)(i + 1);
    }
    o0 = x0; o1 = x1;
}

// ---------------- top-10 + softmax + gumbel categorical, 16 rows ----------------
__global__ __launch_bounds__(256) void k_topk_sample(
    const float* __restrict__ d2row, const unsigned long long* __restrict__ amin,
    const int* __restrict__ mask, int* __restrict__ mlabel, int* __restrict__ negsel)
{
    __shared__ float sd2[KCODE];
    __shared__ unsigned long long rbuf[256];
    __shared__ float rfs[256];
    __shared__ int sel[TOPK];
    __shared__ float selv[TOPK];
    __shared__ float sS;
    int b = blockIdx.x, t = threadIdx.x;
    for (int j = t; j < KCODE; j += 256) sd2[j] = d2row[b * KCODE + j];
    __syncthreads();
    for (int p = 0; p < TOPK; ++p) {
        unsigned long long best = ~0ull;
        for (int j = t; j < KCODE; j += 256) {
            bool skip = false;
            for (int q = 0; q < p; ++q) skip = skip || (j == sel[q]);
            if (skip) continue;
            unsigned long long key =
                ((unsigned long long)__float_as_uint(sd2[j]) << 32) | (unsigned)j;
            best = umin64(best, key);
        }
        rbuf[t] = best;
        __syncthreads();
        for (int s = 128; s > 0; s >>= 1) {
            if (t < s) rbuf[t] = umin64(rbuf[t], rbuf[t + s]);
            __syncthreads();
        }
        if (t == 0) {
            sel[p] = (int)(rbuf[0] & 0xFFFFFFFFull);
            selv[p] = __uint_as_float((uint32_t)(rbuf[0] >> 32));
        }
        __syncthreads();
    }
    float d2min = selv[0];
    float part = 0.0f;
    for (int j = t; j < KCODE; j += 256) part += expf(d2min - sd2[j]);
    part = block_sum(part, rfs);
    if (t == 0) sS = part;
    __syncthreads();
    if (t == 0) {
        int rb = b * 576 + mask[b];
        mlabel[b] = (int)(amin[rb] & 0xFFFFFFFFull);
        float S = sS;
        float bestv = 0.0f;
        int samp = 0;
        bool first = true;
        for (int k = 0; k < TOPK; ++k) {
            float pk = expf(d2min - selv[k]) / S;
            float logit = logf(pk);
            unsigned f = (unsigned)(rb * 10 + k);
            uint32_t o0, o1;
            threefry2x32(0u, f, o0, o1);
            uint32_t bits = o0 ^ o1;
            float uu = __uint_as_float(0x3F800000u | (bits >> 9)) - 1.0f;
            uu = uu + 1.1754944e-38f;
            uu = fmaxf(1.1754944e-38f, uu);
            float gum = -logf(-logf(uu));
            float sc = logit + gum;
            if (first || sc > bestv) { bestv = sc; samp = k; first = false; }
        }
        negsel[b] = sel[samp];
    }
}

// ---------------- final: gate-mix, +pos, two LayerNorms ----------------
__global__ __launch_bounds__(256) void k_final(
    const float* __restrict__ embpt, const float* __restrict__ xq,
    const float* __restrict__ scores, const unsigned long long* __restrict__ amin,
    const int* __restrict__ mlabel, const int* __restrict__ negsel,
    const float* __restrict__ E, const float* __restrict__ pos,
    const float* __restrict__ ow, const float* __restrict__ ob,
    float* __restrict__ outp, float* __restrict__ outn)
{
    __shared__ float red[256];
    int r = blockIdx.x, t = threadIdx.x;
    int b = r / 576, l = r % 576;
    float s0 = scores[r * 2 + 0], s1 = scores[r * 2 + 1];
    int ir = (int)(amin[r] & 0xFFFFFFFFull);
    int nidx = (ir == mlabel[b]) ? negsel[b] : ir;
    const float* ep = embpt + (size_t)r * D_;
    const float* xr = xq + (size_t)r * D_;
    const float* er = E + (size_t)nidx * D_;
    const float* pr = pos + (size_t)l * D_;
    float vp[3], vn[3];
    #pragma unroll
    for (int q = 0; q < 3; ++q) {
        int k = t + q * 256;
        float xv = xr[k] * s1;
        float pv = pr[k];
        vp[q] = (ep[k] * s0 + xv) + pv;
        vn[q] = (er[k] * s0 + xv) + pv;
    }
    float mup = block_sum(vp[0] + vp[1] + vp[2], red) * (1.0f / 768.0f);
    float a0 = vp[0] - mup, a1 = vp[1] - mup, a2 = vp[2] - mup;
    float varp = block_sum(a0 * a0 + a1 * a1 + a2 * a2, red) * (1.0f / 768.0f);
    float rnp = 1.0f / sqrtf(varp + 1e-5f);
    float mun = block_sum(vn[0] + vn[1] + vn[2], red) * (1.0f / 768.0f);
    float c0 = vn[0] - mun, c1 = vn[1] - mun, c2 = vn[2] - mun;
    float varn = block_sum(c0 * c0 + c1 * c1 + c2 * c2, red) * (1.0f / 768.0f);
    float rnn = 1.0f / sqrtf(varn + 1e-5f);
    float* op = outp + (size_t)r * D_;
    float* on = outn + (size_t)r * D_;
    op[t]       = a0 * rnp * ow[t]       + ob[t];
    op[t + 256] = a1 * rnp * ow[t + 256] + ob[t + 256];
    op[t + 512] = a2 * rnp * ow[t + 512] + ob[t + 512];
    on[t]       = c0 * rnn * ow[t]       + ob[t];
    on[t + 256] = c1 * rnn * ow[t + 256] + ob[t + 256];
    on[t + 512] = c2 * rnn * ow[t + 512] + ob[t + 512];
}

// ---------------- launcher ----------------
extern "C" void kernel_launch(void* const* d_in, const int* in_sizes, int n_in,
                              void* d_out, int out_size, void* d_ws, size_t ws_size,
                              hipStream_t stream)
{
    (void)in_sizes; (void)n_in; (void)out_size; (void)ws_size;
    const float* img    = (const float*)d_in[0];
    const int*   maski  = (const int*)d_in[1];
    const float* lin_w  = (const float*)d_in[2];
    const float* lin_b  = (const float*)d_in[3];
    const float* ln1_w  = (const float*)d_in[4];
    const float* ln1_b  = (const float*)d_in[5];
    const float* embed  = (const float*)d_in[6];
    const float* pos_w  = (const float*)d_in[7];
    const float* pos_b  = (const float*)d_in[8];
    const float* gate_w = (const float*)d_in[9];
    const float* gate_b = (const float*)d_in[10];
    const float* glnw   = (const float*)d_in[11];
    const float* glnb   = (const float*)d_in[12];
    const float* olnw   = (const float*)d_in[13];
    const float* olnb   = (const float*)d_in[14];

    uint8_t* wp = (uint8_t*)d_ws;
    auto alloc = [&](size_t bytes) -> void* {
        void* p = (void*)wp;
        wp += (bytes + 255) & ~(size_t)255;
        return p;
    };
    float* bufA = (float*)alloc((size_t)M_TOT * D_ * 4);   // gemm1 out, later emb_pt
    float* xq   = (float*)alloc((size_t)M_TOT * D_ * 4);
    float* xsq  = (float*)alloc((size_t)M_TOT * 4);
    float* esq  = (float*)alloc((size_t)KCODE * 4);
    unsigned long long* amin = (unsigned long long*)alloc((size_t)M_TOT * 8);
    int*   rowflag = (int*)alloc((size_t)M_TOT * 4);
    float* scores = (float*)alloc((size_t)M_TOT * 2 * 4);
    float* posb   = (float*)alloc((size_t)576 * D_ * 4);
    float* d2row  = (float*)alloc((size_t)16 * KCODE * 4);
    int*   mlab   = (int*)alloc(16 * 4);
    int*   negsel = (int*)alloc(16 * 4);
    u16* Wh = (u16*)alloc((size_t)D_ * CIN_ * 2);
    u16* Wm = (u16*)alloc((size_t)D_ * CIN_ * 2);
    u16* Wl = (u16*)alloc((size_t)D_ * CIN_ * 2);
    u16* Ph = (u16*)alloc((size_t)D_ * D_ * 2);
    u16* Pl = (u16*)alloc((size_t)D_ * D_ * 2);
    // R region: img 3-way splits (dead after gemm1), then reused for X/E splits
    u16* R  = (u16*)alloc((size_t)3 * M_TOT * CIN_ * 2);
    u16* Ih = R;
    u16* Im = R + (size_t)M_TOT * CIN_;
    u16* Il = R + (size_t)2 * M_TOT * CIN_;
    u16* Xh = R;
    u16* Xl = Xh + (size_t)M_TOT * D_;
    u16* Eh = Xl + (size_t)M_TOT * D_;
    u16* El = Eh + (size_t)KCODE * D_;

    float* outp = (float*)d_out;
    float* outn = outp + (size_t)M_TOT * D_;

    hipMemsetAsync(amin, 0xFF, M_TOT * sizeof(unsigned long long), stream);

    dim3 blk(256);
    // 0) merged prep: img/lin_w/pos_w splits + pos encoding + rowflag
    k_prep<<<11172, blk, 0, stream>>>(img, Ih, Im, Il, lin_w, Wh, Wm, Wl,
                                      pos_w, Ph, Pl, posb, maski, rowflag);
    // 1) xq_pre = img @ lin_w^T + lin_b   (3-way split, 6-term MFMA, swizzled)
    k_gemm1_mfma<<<dim3(D_ / 128, M_TOT / 128), blk, 0, stream>>>(
        Ih, Im, Il, Wh, Wm, Wl, lin_b, bufA);
    // 2) merged: LN+ReLU+xsq+X-split | esq+E-split (E region now dead-aliased OK)
    k_ln_esq<<<17408, blk, 0, stream>>>(bufA, ln1_w, ln1_b, xq, xsq, Xh, Xl,
                                        embed, esq, Eh, El);
    // 3) fused code-search MFMA GEMM + argmin + masked-row d2 capture
    k_gemm2_mfma<<<dim3(KCODE / 128, M_TOT / 128), blk, 0, stream>>>(
        Xh, Xl, Eh, El, xsq, esq, rowflag, d2row, amin);
    // 4) emb_pt = embed[idx] @ pos_w^T + pos_b  (idx read from amin low bits)
    k_gemm3_mfma<<<dim3(D_ / 128, M_TOT / 128), blk, 0, stream>>>(
        Eh, El, Ph, Pl, amin, pos_b, bufA);
    // 5) gate scores
    k_gate<<<M_TOT, blk, 0, stream>>>(bufA, xq, gate_w, gate_b, glnw, glnb, scores);
    // 6) top-10 + threefry gumbel categorical (d2row from gemm2 epilogue)
    k_topk_sample<<<16, blk, 0, stream>>>(d2row, amin, maski, mlab, negsel);
    // 7) final mix + LN x2
    k_final<<<M_TOT, blk, 0, stream>>>(bufA, xq, scores, amin, mlab, negsel,
                                       embed, posb, olnw, olnb, outp, outn);
}